// Round 1
// baseline (7368.446 us; speedup 1.0000x reference)
//
#include <hip/hip_runtime.h>
#include <math.h>

#define NN 50000
#define HH 256
#define RR 460
#define TT 3
#define EE 100000
#define PP 3
#define SLOPE 0.22916666666666666f

static const size_t NHf = (size_t)NN * HH;   // 12.8M floats

__device__ __forceinline__ float sigm(float x){ return 1.0f/(1.0f+__expf(-x)); }

// ---------------- transpose: out[K][M] = in[M][K]^T ----------------
__global__ __launch_bounds__(256) void transpose_k(const float* __restrict__ in,
                                                   float* __restrict__ out, int M, int K){
  __shared__ float tile[32][33];
  int k0 = blockIdx.x*32, m0 = blockIdx.y*32;
  int tx = threadIdx.x & 31, ty = threadIdx.x >> 5;
  #pragma unroll
  for (int j=0;j<4;j++){
    int m = m0 + ty + j*8, k = k0 + tx;
    tile[ty+j*8][tx] = (m<M && k<K) ? in[(size_t)m*K+k] : 0.f;
  }
  __syncthreads();
  #pragma unroll
  for (int j=0;j<4;j++){
    int k = k0 + ty + j*8, m = m0 + tx;
    if (k<K && m<M) out[(size_t)k*M+m] = tile[tx][ty+j*8];
  }
}

// split W_hp [256][259] into W_hpT [256(k)][256(j)] and W_hpP [3][256]
__global__ __launch_bounds__(256) void whp_split_k(const float* __restrict__ W_hp,
                                                   float* __restrict__ WT, float* __restrict__ WP){
  int j = blockIdx.x;          // output neuron
  int k = threadIdx.x;         // input dim
  WT[(size_t)k*HH + j] = W_hp[(size_t)j*259 + k];
  if (k < PP) WP[k*HH + j] = W_hp[(size_t)j*259 + HH + k];
}

// ---------------- SGEMM: C[M][N] = A[M][K] @ B[K][N] (+bias per col) ----------------
// BM=128 BN=64 BK=16, 256 threads, 8x4 micro-tile. N%64==0, K%16==0 required.
__global__ __launch_bounds__(256) void sgemm_k(const float* __restrict__ A, const float* __restrict__ B,
                                               float* __restrict__ C, const float* __restrict__ bias,
                                               int M, int N, int K){
  __shared__ float As[16][128];
  __shared__ float Bs[16][64];
  int tid = threadIdx.x;
  int tx = tid & 15, ty = tid >> 4;
  int rowBase = blockIdx.x * 128;
  int colBase = blockIdx.y * 64;
  float acc[8][4];
  #pragma unroll
  for (int i=0;i<8;i++)
    #pragma unroll
    for (int j=0;j<4;j++) acc[i][j]=0.f;

  for (int k0=0;k0<K;k0+=16){
    #pragma unroll
    for (int ss=0; ss<2; ss++){
      int s = tid + ss*256;
      int r = s >> 2;              // 0..127
      int kk = (s & 3)*4;          // 0,4,8,12
      float4 v = make_float4(0.f,0.f,0.f,0.f);
      int grow = rowBase + r;
      if (grow < M) v = *(const float4*)(A + (size_t)grow*K + k0 + kk);
      As[kk+0][r]=v.x; As[kk+1][r]=v.y; As[kk+2][r]=v.z; As[kk+3][r]=v.w;
    }
    {
      int r = tid >> 4, cc = (tid & 15)*4;
      float4 v = *(const float4*)(B + (size_t)(k0+r)*N + colBase + cc);
      *(float4*)&Bs[r][cc] = v;
    }
    __syncthreads();
    #pragma unroll
    for (int kk=0;kk<16;kk++){
      float a[8], b[4];
      *(float4*)&a[0] = *(const float4*)&As[kk][ty*8];
      *(float4*)&a[4] = *(const float4*)&As[kk][ty*8+4];
      *(float4*)&b[0] = *(const float4*)&Bs[kk][tx*4];
      #pragma unroll
      for (int i=0;i<8;i++)
        #pragma unroll
        for (int j=0;j<4;j++)
          acc[i][j] = fmaf(a[i], b[j], acc[i][j]);
    }
    __syncthreads();
  }
  float4 bb = make_float4(0.f,0.f,0.f,0.f);
  if (bias) bb = *(const float4*)(bias + colBase + tx*4);
  #pragma unroll
  for (int i=0;i<8;i++){
    int gr = rowBase + ty*8 + i;
    if (gr >= M) continue;
    float4 v = make_float4(acc[i][0]+bb.x, acc[i][1]+bb.y, acc[i][2]+bb.z, acc[i][3]+bb.w);
    *(float4*)(C + (size_t)gr*N + colBase + tx*4) = v;
  }
}

// ---------------- row-wise L2 normalize (in==out allowed) ----------------
__global__ __launch_bounds__(256) void l2norm_k(const float* __restrict__ in, float* __restrict__ outp){
  int i = blockIdx.x, c = threadIdx.x;
  size_t idx = (size_t)i*HH + c;
  float v = in[idx];
  float ss = v*v;
  #pragma unroll
  for (int o=32;o;o>>=1) ss += __shfl_down(ss, o);
  __shared__ float red[4];
  if ((threadIdx.x & 63)==0) red[threadIdx.x>>6] = ss;
  __syncthreads();
  float tot = red[0]+red[1]+red[2]+red[3];
  float inv = 1.0f / fmaxf(sqrtf(tot), 1e-12f);
  outp[idx] = v * inv;
}

// ---------------- per-relation mean scatter ----------------
__global__ __launch_bounds__(256) void scatter_xsum_k(const float* __restrict__ h,
    const int* __restrict__ r_to_e, const int* __restrict__ r_seg,
    float* __restrict__ xsums, float* __restrict__ cnts){
  int g = blockIdx.x*blockDim.x + threadIdx.x;
  int e = g >> 6, lane = g & 63;
  if (e >= EE) return;
  int v = r_to_e[e], r = r_seg[e];
  float4 a = *(const float4*)(h + (size_t)v*HH + lane*4);
  float* o = xsums + (size_t)r*HH + lane*4;
  atomicAdd(o+0,a.x); atomicAdd(o+1,a.y); atomicAdd(o+2,a.z); atomicAdd(o+3,a.w);
  if (lane==0) atomicAdd(cnts + r, 1.0f);
}

__global__ __launch_bounds__(256) void build_xin_k(const float* __restrict__ emb_rel,
    const float* __restrict__ xsums, const float* __restrict__ cnts, float* __restrict__ xin){
  int r = blockIdx.x, c = threadIdx.x;
  float cnt = cnts[r];
  float mean = (cnt > 0.f) ? xsums[(size_t)r*HH + c] / cnt : 0.f;
  xin[(size_t)r*2*HH + c]      = emb_rel[(size_t)r*HH + c];
  xin[(size_t)r*2*HH + HH + c] = mean;
}

// ---------------- GRU gates + row l2norm, in-place h0 ----------------
__global__ __launch_bounds__(256) void gru_gate_k(const float* __restrict__ gi,
    const float* __restrict__ ghb, float* __restrict__ h0){
  int r = blockIdx.x, c = threadIdx.x;
  float ir = gi[(size_t)r*768 + c],      hr = ghb[(size_t)r*768 + c];
  float iz = gi[(size_t)r*768 + 256 + c], hz = ghb[(size_t)r*768 + 256 + c];
  float in_ = gi[(size_t)r*768 + 512 + c], hn = ghb[(size_t)r*768 + 512 + c];
  float rg = sigm(ir + hr);
  float z  = sigm(iz + hz);
  float n  = tanhf(in_ + rg*hn);
  float hp = h0[(size_t)r*HH + c];
  float v = (1.f - z)*n + z*hp;
  float ss = v*v;
  #pragma unroll
  for (int o=32;o;o>>=1) ss += __shfl_down(ss, o);
  __shared__ float red[4];
  if ((threadIdx.x & 63)==0) red[threadIdx.x>>6] = ss;
  __syncthreads();
  float tot = red[0]+red[1]+red[2]+red[3];
  float inv = 1.0f / fmaxf(sqrtf(tot), 1e-12f);
  h0[(size_t)r*HH + c] = v * inv;
}

// ---------------- degree ----------------
__global__ __launch_bounds__(256) void scatter_deg_k(const int* __restrict__ dst, float* __restrict__ deg){
  int e = blockIdx.x*blockDim.x + threadIdx.x;
  if (e < EE) atomicAdd(deg + dst[e], 1.0f);
}

// ---------------- edge message scatter: tmp[dst] += nh[src] + h0[etype] ----------------
__global__ __launch_bounds__(256) void scatter_msg_k(const float* __restrict__ nh,
    const float* __restrict__ h0, const int* __restrict__ src, const int* __restrict__ dst,
    const int* __restrict__ etype, float* __restrict__ tmp){
  int g = blockIdx.x*blockDim.x + threadIdx.x;
  int e = g >> 6, lane = g & 63;
  if (e >= EE) return;
  int s = src[e], d = dst[e], r = etype[e];
  float4 a = *(const float4*)(nh + (size_t)s*HH + lane*4);
  float4 b = *(const float4*)(h0 + (size_t)r*HH + lane*4);
  float* o = tmp + (size_t)d*HH + lane*4;
  atomicAdd(o+0, a.x+b.x); atomicAdd(o+1, a.y+b.y);
  atomicAdd(o+2, a.z+b.z); atomicAdd(o+3, a.w+b.w);
}

// ---------------- layer combine: nh_out = leaky(agg*norm + (deg>0 ? loop : evolve)) ----------------
__global__ __launch_bounds__(256) void combine_k(const float* __restrict__ c1, const float* __restrict__ c2,
    const float* __restrict__ c3, const float* __restrict__ deg, float* __restrict__ outp){
  int i = blockIdx.x, c = threadIdx.x;
  float d = deg[i];
  size_t idx = (size_t)i*HH + c;
  float agg = (d > 0.f) ? c1[idx] / d : 0.f;
  float lp  = (d > 0.f) ? c2[idx] : c3[idx];
  float pre = agg + lp;
  outp[idx] = (pre >= 0.f) ? pre : SLOPE*pre;
}

// ---------------- attention pos-fix + tanh (in-place) ----------------
__global__ __launch_bounds__(256) void attn_fix_k(float* __restrict__ attn, const float* __restrict__ pos,
    const float* __restrict__ WP, const float* __restrict__ b_hp){
  int i = blockIdx.x, c = threadIdx.x;
  float p0 = pos[(size_t)i*PP], p1 = pos[(size_t)i*PP+1], p2 = pos[(size_t)i*PP+2];
  size_t idx = (size_t)i*HH + c;
  float v = attn[idx] + p0*WP[c] + p1*WP[HH+c] + p2*WP[2*HH+c] + b_hp[c];
  attn[idx] = tanhf(v);
}

// ---------------- h update: h = sig(gate)*curn + (1-sig)*h ----------------
__global__ __launch_bounds__(256) void update_h_k(float* __restrict__ h, const float* __restrict__ curn,
    const float* __restrict__ gate){
  int i = blockIdx.x, c = threadIdx.x;
  size_t idx = (size_t)i*HH + c;
  float s = sigm(gate[idx]);
  h[idx] = s*curn[idx] + (1.f-s)*h[idx];
}

// ---------------- out write: out = sig(gate)*global_h + (1-sig)*h ----------------
__global__ __launch_bounds__(256) void out_write_k(const float* __restrict__ h, const float* __restrict__ gh,
    const float* __restrict__ gate, float* __restrict__ outp){
  int i = blockIdx.x, c = threadIdx.x;
  size_t idx = (size_t)i*HH + c;
  float s = sigm(gate[idx]);
  outp[idx] = s*gh[idx] + (1.f-s)*h[idx];
}

extern "C" void kernel_launch(void* const* d_in, const int* in_sizes, int n_in,
                              void* d_out, int out_size, void* d_ws, size_t ws_size,
                              hipStream_t stream) {
  const int*   src     = (const int*)  d_in[0];
  const int*   dst     = (const int*)  d_in[1];
  const int*   etype   = (const int*)  d_in[2];
  const int*   r_to_e  = (const int*)  d_in[3];
  const int*   r_seg   = (const int*)  d_in[4];
  const float* pos_enc = (const float*)d_in[5];
  const float* dyn_emb = (const float*)d_in[6];
  const float* emb_rel = (const float*)d_in[7];
  const float* gW_ih   = (const float*)d_in[8];
  const float* gW_hh   = (const float*)d_in[9];
  const float* gb_ih   = (const float*)d_in[10];
  const float* gb_hh   = (const float*)d_in[11];
  const float* W_neigh = (const float*)d_in[12];
  const float* W_loop  = (const float*)d_in[13];
  const float* W_evolve= (const float*)d_in[14];
  const float* W_hp    = (const float*)d_in[15];
  const float* b_hp    = (const float*)d_in[16];
  const float* W_v     = (const float*)d_in[17];
  const float* b_v     = (const float*)d_in[18];
  const float* W_o     = (const float*)d_in[19];
  const float* b_o     = (const float*)d_in[20];
  const float* time_W  = (const float*)d_in[21];
  const float* time_b  = (const float*)d_in[22];
  const float* glob_W  = (const float*)d_in[23];
  const float* glob_b  = (const float*)d_in[24];
  float* out = (float*)d_out;

  char* ws = (char*)d_ws;
  size_t off = 0;
  auto alloc = [&](size_t nfloats)->float*{
    float* p = (float*)(ws + off); off += nfloats*sizeof(float);
    return p;
  };
  float* h    = alloc(NHf);
  float* nh   = alloc(NHf);
  float* nh2  = alloc(NHf);
  float* tmp  = alloc(NHf);   // scatter accum / gate buffer
  float* c1   = alloc(NHf);   // agg / attn
  float* c2   = alloc(NHf);   // loop / vh
  float* c3   = alloc(NHf);   // evolve / global_h
  float* h0   = alloc((size_t)RR*HH);
  float* xsums= alloc((size_t)RR*HH);
  float* xin  = alloc((size_t)RR*2*HH);
  float* gi   = alloc((size_t)RR*768);
  float* ghb  = alloc((size_t)RR*768);
  float* cnts = alloc(RR);
  float* deg  = alloc(NN);
  float* W_ihT= alloc((size_t)512*768);
  float* W_hhT= alloc((size_t)256*768);
  float* W_vT = alloc((size_t)256*256);
  float* W_oT = alloc((size_t)256*256);
  float* W_hpT= alloc((size_t)256*256);
  float* W_hpP= alloc((size_t)3*256);
  (void)ws_size; (void)in_sizes; (void)n_in; (void)out_size;

  auto GEMM = [&](const float* A, const float* B, float* C, const float* bias, int M, int N, int K){
    dim3 g((M+127)/128, N/64);
    sgemm_k<<<g, 256, 0, stream>>>(A, B, C, bias, M, N, K);
  };

  // ---- setup: transpose weights, init h and h0 ----
  transpose_k<<<dim3(512/32, 768/32), 256, 0, stream>>>(gW_ih, W_ihT, 768, 512);
  transpose_k<<<dim3(256/32, 768/32), 256, 0, stream>>>(gW_hh, W_hhT, 768, 256);
  transpose_k<<<dim3(8, 8), 256, 0, stream>>>(W_v, W_vT, 256, 256);
  transpose_k<<<dim3(8, 8), 256, 0, stream>>>(W_o, W_oT, 256, 256);
  whp_split_k<<<256, 256, 0, stream>>>(W_hp, W_hpT, W_hpP);
  l2norm_k<<<NN, 256, 0, stream>>>(dyn_emb, h);
  hipMemcpyAsync(h0, emb_rel, (size_t)RR*HH*sizeof(float), hipMemcpyDeviceToDevice, stream);

  for (int t=0; t<TT; t++){
    const int* srcT = src + (size_t)t*EE;
    const int* dstT = dst + (size_t)t*EE;
    const int* etyT = etype + (size_t)t*EE;
    const int* rteT = r_to_e + (size_t)t*EE;
    const int* rsgT = r_seg + (size_t)t*EE;
    const float* posT = pos_enc + (size_t)t*NN*PP;

    // ---- relation mean + GRU ----
    hipMemsetAsync(xsums, 0, (size_t)RR*HH*sizeof(float), stream);
    hipMemsetAsync(cnts, 0, RR*sizeof(float), stream);
    scatter_xsum_k<<<(EE*64+255)/256, 256, 0, stream>>>(h, rteT, rsgT, xsums, cnts);
    build_xin_k<<<RR, 256, 0, stream>>>(emb_rel, xsums, cnts, xin);
    GEMM(xin, W_ihT, gi, gb_ih, RR, 768, 512);
    GEMM(h0,  W_hhT, ghb, gb_hh, RR, 768, 256);
    gru_gate_k<<<RR, 256, 0, stream>>>(gi, ghb, h0);

    // ---- degrees ----
    hipMemsetAsync(deg, 0, NN*sizeof(float), stream);
    scatter_deg_k<<<(EE+255)/256, 256, 0, stream>>>(dstT, deg);

    // ---- RGCN layers ----
    const float* nin = h;
    float* nout = nh;
    for (int l=0; l<2; l++){
      hipMemsetAsync(tmp, 0, NHf*sizeof(float), stream);
      scatter_msg_k<<<(EE*64+255)/256, 256, 0, stream>>>(nin, h0, srcT, dstT, etyT, tmp);
      GEMM(tmp, W_neigh + (size_t)l*HH*HH, c1, nullptr, NN, HH, HH);
      GEMM(nin, W_loop  + (size_t)l*HH*HH, c2, nullptr, NN, HH, HH);
      GEMM(nin, W_evolve+ (size_t)l*HH*HH, c3, nullptr, NN, HH, HH);
      combine_k<<<NN, 256, 0, stream>>>(c1, c2, c3, deg, nout);
      nin = nout;
      nout = nh2;
    }
    // current_h = nh2 (written by layer 1; layer0 wrote nh)

    // ---- attention chain (uses un-normalized current_h) ----
    GEMM(nh2, W_hpT, c1, nullptr, NN, HH, HH);
    attn_fix_k<<<NN, 256, 0, stream>>>(c1, posT, W_hpP, b_hp);
    GEMM(c1, W_vT, c2, b_v, NN, HH, HH);
    GEMM(c2, W_oT, c3, b_o, NN, HH, HH);   // c3 = global_h

    // ---- normalize current_h, time gate, glob gate ----
    l2norm_k<<<NN, 256, 0, stream>>>(nh2, nh2);
    GEMM(h, time_W, tmp, time_b, NN, HH, HH);
    update_h_k<<<NN, 256, 0, stream>>>(h, nh2, tmp);
    GEMM(h, glob_W, tmp, glob_b, NN, HH, HH);
    out_write_k<<<NN, 256, 0, stream>>>(h, c3, tmp, out + (size_t)t*NHf);
  }
}

// Round 2
// 4381.603 us; speedup vs baseline: 1.6817x; 1.6817x over previous
//
#include <hip/hip_runtime.h>
#include <math.h>

#define NN 50000
#define HH 256
#define RR 460
#define TT 3
#define EE 100000
#define PP 3
#define SLOPE 0.22916666666666666f

typedef __bf16 bf16_t;
typedef bf16_t bf16x8 __attribute__((ext_vector_type(8)));
typedef float f32x4 __attribute__((ext_vector_type(4)));

static const size_t NHf = (size_t)NN * HH;   // 12.8M elements

__device__ __forceinline__ float sigm(float x){ return 1.0f/(1.0f+__expf(-x)); }

__device__ __forceinline__ void gload_lds16(const void* g, void* l){
  __builtin_amdgcn_global_load_lds((const __attribute__((address_space(1))) void*)g,
                                   (__attribute__((address_space(3))) void*)l, 16, 0, 0);
}

// ---------------- f32 transpose (GRU weights): out[K][M] = in[M][K]^T ----------------
__global__ __launch_bounds__(256) void transpose_k(const float* __restrict__ in,
                                                   float* __restrict__ out, int M, int K){
  __shared__ float tile[32][33];
  int k0 = blockIdx.x*32, m0 = blockIdx.y*32;
  int tx = threadIdx.x & 31, ty = threadIdx.x >> 5;
  #pragma unroll
  for (int j=0;j<4;j++){
    int m = m0 + ty + j*8, k = k0 + tx;
    tile[ty+j*8][tx] = (m<M && k<K) ? in[(size_t)m*K+k] : 0.f;
  }
  __syncthreads();
  #pragma unroll
  for (int j=0;j<4;j++){
    int k = k0 + ty + j*8, m = m0 + tx;
    if (k<K && m<M) out[(size_t)k*M+m] = tile[tx][ty+j*8];
  }
}

// ---------------- transpose+convert 256x256 f32 -> bf16: out[n*256+k] = in[k*256+n] ----------------
__global__ __launch_bounds__(256) void tconv_bf_k(const float* __restrict__ in, bf16_t* __restrict__ outp){
  __shared__ float tile[32][33];
  int n0 = blockIdx.x*32, k0 = blockIdx.y*32;
  int tx = threadIdx.x & 31, ty = threadIdx.x >> 5;
  #pragma unroll
  for (int j=0;j<4;j++)
    tile[ty+j*8][tx] = in[(size_t)(k0+ty+j*8)*256 + n0+tx];
  __syncthreads();
  #pragma unroll
  for (int j=0;j<4;j++)
    outp[(size_t)(n0+ty+j*8)*256 + k0+tx] = (bf16_t)tile[tx][ty+j*8];
}

// ---------------- row copy+convert: out[r][c] = (bf16)in[r*Cin + c], c<256 ----------------
__global__ __launch_bounds__(256) void copy_bf_k(const float* __restrict__ in, bf16_t* __restrict__ outp, int Cin){
  int r = blockIdx.x, c = threadIdx.x;
  outp[(size_t)r*HH + c] = (bf16_t)in[(size_t)r*Cin + c];
}

// WP[p][j] = W_hp[j*259 + 256 + p]
__global__ __launch_bounds__(256) void whp_pos_k(const float* __restrict__ W_hp, float* __restrict__ WP){
  int j = threadIdx.x;
  #pragma unroll
  for (int p=0;p<PP;p++) WP[p*HH + j] = W_hp[(size_t)j*259 + HH + p];
}

// ---------------- f32 SGEMM (GRU only): C[M][N] = A[M][K] @ B[K][N] + bias ----------------
__global__ __launch_bounds__(256) void sgemm_k(const float* __restrict__ A, const float* __restrict__ B,
                                               float* __restrict__ C, const float* __restrict__ bias,
                                               int M, int N, int K){
  __shared__ float As[16][128];
  __shared__ float Bs[16][64];
  int tid = threadIdx.x;
  int tx = tid & 15, ty = tid >> 4;
  int rowBase = blockIdx.x * 128;
  int colBase = blockIdx.y * 64;
  float acc[8][4];
  #pragma unroll
  for (int i=0;i<8;i++)
    #pragma unroll
    for (int j=0;j<4;j++) acc[i][j]=0.f;
  for (int k0=0;k0<K;k0+=16){
    #pragma unroll
    for (int ss=0; ss<2; ss++){
      int s = tid + ss*256;
      int r = s >> 2;
      int kk = (s & 3)*4;
      float4 v = make_float4(0.f,0.f,0.f,0.f);
      int grow = rowBase + r;
      if (grow < M) v = *(const float4*)(A + (size_t)grow*K + k0 + kk);
      As[kk+0][r]=v.x; As[kk+1][r]=v.y; As[kk+2][r]=v.z; As[kk+3][r]=v.w;
    }
    {
      int r = tid >> 4, cc = (tid & 15)*4;
      float4 v = *(const float4*)(B + (size_t)(k0+r)*N + colBase + cc);
      *(float4*)&Bs[r][cc] = v;
    }
    __syncthreads();
    #pragma unroll
    for (int kk=0;kk<16;kk++){
      float a[8], b[4];
      *(float4*)&a[0] = *(const float4*)&As[kk][ty*8];
      *(float4*)&a[4] = *(const float4*)&As[kk][ty*8+4];
      *(float4*)&b[0] = *(const float4*)&Bs[kk][tx*4];
      #pragma unroll
      for (int i=0;i<8;i++)
        #pragma unroll
        for (int j=0;j<4;j++)
          acc[i][j] = fmaf(a[i], b[j], acc[i][j]);
    }
    __syncthreads();
  }
  float4 bb = make_float4(0.f,0.f,0.f,0.f);
  if (bias) bb = *(const float4*)(bias + colBase + tx*4);
  #pragma unroll
  for (int i=0;i<8;i++){
    int gr = rowBase + ty*8 + i;
    if (gr >= M) continue;
    float4 v = make_float4(acc[i][0]+bb.x, acc[i][1]+bb.y, acc[i][2]+bb.z, acc[i][3]+bb.w);
    *(float4*)(C + (size_t)gr*N + colBase + tx*4) = v;
  }
}

// ---------------- bf16 MFMA GEMM: C[M][N] = A[M][K] @ Bt[N][K]^T ----------------
// A, Bt bf16 row-major. BM=BN=128, BK=64, 256 threads (4 waves 2x2).
// LDS layout: [128 rows][8 segs of 16B], seg swizzle s_phys = s ^ (row&7) applied
// on BOTH the global source (pre-swizzle) and the ds_read (rule #21 / m201).
template<int WF32, int WBF, int HASB>
__global__ __launch_bounds__(256) void mgemm_k(const bf16_t* __restrict__ A, const bf16_t* __restrict__ Bt,
    float* __restrict__ C, bf16_t* __restrict__ Cb, const float* __restrict__ bias,
    int M, int N, int K){
  __shared__ bf16_t As[128*64];
  __shared__ bf16_t Bs[128*64];
  int tid = threadIdx.x;
  int lane = tid & 63, w = tid >> 6;
  int wm = w >> 1, wn = w & 1;
  int rowBase = blockIdx.x * 128;
  int colBase = blockIdx.y * 128;
  f32x4 acc[4][4] = {};

  int lrow = lane >> 3;          // 0..7 within the wave's 8-row group
  int p    = lane & 7;           // phys 16B seg
  for (int k0 = 0; k0 < K; k0 += 64){
    #pragma unroll
    for (int c = 0; c < 4; c++){
      int r = c*32 + w*8 + lrow;               // tile row 0..127
      int s = p ^ (r & 7);                     // logical seg to fetch
      int ga = min(rowBase + r, M-1);          // clamp: garbage rows feed unused acc rows only
      gload_lds16(A + (size_t)ga*K + k0 + s*8, As + (size_t)(c*32 + w*8)*64);
      int gb = colBase + r;                    // N is always a multiple of 128 here
      gload_lds16(Bt + (size_t)gb*K + k0 + s*8, Bs + (size_t)(c*32 + w*8)*64);
    }
    asm volatile("s_waitcnt vmcnt(0)" ::: "memory");
    __syncthreads();
    #pragma unroll
    for (int kk = 0; kk < 2; kk++){
      bf16x8 af[4], bfr[4];
      int sg = kk*4 + (lane >> 4);             // logical seg 0..7
      #pragma unroll
      for (int i = 0; i < 4; i++){
        int r = wm*64 + i*16 + (lane & 15);
        af[i] = *(const bf16x8*)(As + r*64 + (sg ^ (r & 7))*8);
      }
      #pragma unroll
      for (int j = 0; j < 4; j++){
        int rn = wn*64 + j*16 + (lane & 15);
        bfr[j] = *(const bf16x8*)(Bs + rn*64 + (sg ^ (rn & 7))*8);
      }
      #pragma unroll
      for (int i = 0; i < 4; i++)
        #pragma unroll
        for (int j = 0; j < 4; j++)
          acc[i][j] = __builtin_amdgcn_mfma_f32_16x16x32_bf16(af[i], bfr[j], acc[i][j], 0, 0, 0);
    }
    __syncthreads();
  }
  #pragma unroll
  for (int j = 0; j < 4; j++){
    int col = colBase + wn*64 + j*16 + (lane & 15);
    float bv = 0.f;
    if (HASB) bv = bias[col];
    #pragma unroll
    for (int i = 0; i < 4; i++){
      int row0 = rowBase + wm*64 + i*16 + ((lane >> 4) << 2);
      #pragma unroll
      for (int q = 0; q < 4; q++){
        int gr = row0 + q;
        if (gr < M){
          float v = acc[i][j][q] + bv;
          if (WF32) C[(size_t)gr*N + col] = v;
          if (WBF)  Cb[(size_t)gr*N + col] = (bf16_t)v;
        }
      }
    }
  }
}

// ---------------- row-wise L2 normalize -> f32 + bf16 (setup) ----------------
__global__ __launch_bounds__(256) void l2norm_k(const float* __restrict__ in, float* __restrict__ outf,
                                                bf16_t* __restrict__ outb){
  int i = blockIdx.x, c = threadIdx.x;
  size_t idx = (size_t)i*HH + c;
  float v = in[idx];
  float ss = v*v;
  #pragma unroll
  for (int o=32;o;o>>=1) ss += __shfl_down(ss, o);
  __shared__ float red[4];
  if ((threadIdx.x & 63)==0) red[threadIdx.x>>6] = ss;
  __syncthreads();
  float tot = red[0]+red[1]+red[2]+red[3];
  float nv = v / fmaxf(sqrtf(tot), 1e-12f);
  outf[idx] = nv;
  outb[idx] = (bf16_t)nv;
}

// ---------------- relation CSR ----------------
__global__ __launch_bounds__(256) void hist_r_k(const int* __restrict__ r_seg, int* __restrict__ cnt){
  int e = blockIdx.x*256 + threadIdx.x;
  if (e < EE) atomicAdd(cnt + r_seg[e], 1);
}
__global__ __launch_bounds__(512) void scan_r_k(const int* __restrict__ cnt, int* __restrict__ start){
  __shared__ int s[512];
  int t = threadIdx.x;
  int v = (t < RR) ? cnt[t] : 0;
  s[t] = v; __syncthreads();
  for (int off=1; off<512; off<<=1){
    int x = (t>=off) ? s[t-off] : 0;
    __syncthreads();
    s[t] += x;
    __syncthreads();
  }
  if (t < RR) start[t] = s[t] - v;
  if (t == RR-1) start[RR] = s[t];
}
__global__ __launch_bounds__(256) void fill_r_k(const int* __restrict__ r_seg, int* __restrict__ cur,
                                                int* __restrict__ bucket){
  int e = blockIdx.x*256 + threadIdx.x;
  if (e < EE){ int pp = atomicAdd(cur + r_seg[e], 1); bucket[pp] = e; }
}
// per-relation mean of h rows + xin build: xin[r] = [emb_rel[r] | mean]
__global__ __launch_bounds__(256) void rmean_k(const int* __restrict__ rstart, const int* __restrict__ rbucket,
    const int* __restrict__ r_to_e, const bf16_t* __restrict__ hb,
    const float* __restrict__ emb_rel, float* __restrict__ xin){
  int r = blockIdx.x, c = threadIdx.x;
  int s0 = rstart[r], s1 = rstart[r+1];
  float acc = 0.f;
  for (int i = s0; i < s1; i++){
    int v = r_to_e[rbucket[i]];
    acc += (float)hb[(size_t)v*HH + c];
  }
  int cnt = s1 - s0;
  xin[(size_t)r*512 + c] = emb_rel[(size_t)r*HH + c];
  xin[(size_t)r*512 + HH + c] = (cnt > 0) ? acc/(float)cnt : 0.f;
}

// ---------------- GRU gates + row l2norm, in-place h0 (f32) ----------------
__global__ __launch_bounds__(256) void gru_gate_k(const float* __restrict__ gi,
    const float* __restrict__ ghb, float* __restrict__ h0){
  int r = blockIdx.x, c = threadIdx.x;
  float ir = gi[(size_t)r*768 + c],       hr = ghb[(size_t)r*768 + c];
  float iz = gi[(size_t)r*768 + 256 + c], hz = ghb[(size_t)r*768 + 256 + c];
  float in_ = gi[(size_t)r*768 + 512 + c], hn = ghb[(size_t)r*768 + 512 + c];
  float rg = sigm(ir + hr);
  float z  = sigm(iz + hz);
  float n  = tanhf(in_ + rg*hn);
  float hp = h0[(size_t)r*HH + c];
  float v = (1.f - z)*n + z*hp;
  float ss = v*v;
  #pragma unroll
  for (int o=32;o;o>>=1) ss += __shfl_down(ss, o);
  __shared__ float red[4];
  if ((threadIdx.x & 63)==0) red[threadIdx.x>>6] = ss;
  __syncthreads();
  float tot = red[0]+red[1]+red[2]+red[3];
  h0[(size_t)r*HH + c] = v / fmaxf(sqrtf(tot), 1e-12f);
}

// ---------------- degree ----------------
__global__ __launch_bounds__(256) void hist_deg_k(const int* __restrict__ dst, float* __restrict__ deg){
  int e = blockIdx.x*256 + threadIdx.x;
  if (e < EE) atomicAdd(deg + dst[e], 1.0f);
}

// ---------------- edge message scatter: tmp[dst] += nh_bf[src] + h0[etype] ----------------
__global__ __launch_bounds__(256) void scatter_msg_k(const bf16_t* __restrict__ nhb,
    const float* __restrict__ h0, const int* __restrict__ src, const int* __restrict__ dst,
    const int* __restrict__ etype, float* __restrict__ tmp){
  int g = blockIdx.x*256 + threadIdx.x;
  int e = g >> 6, ln = g & 63;
  if (e >= EE) return;
  int s = src[e], d = dst[e], r = etype[e];
  uint2 raw = *(const uint2*)(nhb + (size_t)s*HH + ln*4);
  float4 b = *(const float4*)(h0 + (size_t)r*HH + ln*4);
  float a0 = __uint_as_float((raw.x & 0xffffu) << 16);
  float a1 = __uint_as_float(raw.x & 0xffff0000u);
  float a2 = __uint_as_float((raw.y & 0xffffu) << 16);
  float a3 = __uint_as_float(raw.y & 0xffff0000u);
  float* o = tmp + (size_t)d*HH + ln*4;
  atomicAdd(o+0, a0+b.x); atomicAdd(o+1, a1+b.y);
  atomicAdd(o+2, a2+b.z); atomicAdd(o+3, a3+b.w);
}

// ---------------- f32 -> bf16 convert (vectorized) ----------------
__global__ __launch_bounds__(256) void f2b_k(const float* __restrict__ in, bf16_t* __restrict__ outp, int n8){
  int i = blockIdx.x*256 + threadIdx.x;
  if (i >= n8) return;
  f32x4 a = ((const f32x4*)in)[2*(size_t)i];
  f32x4 b = ((const f32x4*)in)[2*(size_t)i+1];
  bf16x8 o;
  #pragma unroll
  for (int j=0;j<4;j++){ o[j] = (bf16_t)a[j]; o[j+4] = (bf16_t)b[j]; }
  ((bf16x8*)outp)[i] = o;
}

// ---------------- layer combine: out = leaky(agg/deg + (deg>0 ? loop : evolve)) ----------------
__global__ __launch_bounds__(256) void combine_k(const bf16_t* __restrict__ agg, const bf16_t* __restrict__ le,
    const float* __restrict__ deg, float* __restrict__ outf, bf16_t* __restrict__ outb){
  int i = blockIdx.x, c = threadIdx.x;
  float d = deg[i];
  size_t idx = (size_t)i*HH + c;
  float a  = (d > 0.f) ? (float)agg[idx] / d : 0.f;
  float lp = (d > 0.f) ? (float)le[(size_t)i*512 + c] : (float)le[(size_t)i*512 + HH + c];
  float pre = a + lp;
  float v = (pre >= 0.f) ? pre : SLOPE*pre;
  if (outf) outf[idx] = v;
  outb[idx] = (bf16_t)v;
}

// ---------------- attention pos-fix + tanh (in-place bf16) ----------------
__global__ __launch_bounds__(256) void attn_fix_k(bf16_t* __restrict__ attn, const float* __restrict__ pos,
    const float* __restrict__ WP, const float* __restrict__ b_hp){
  int i = blockIdx.x, c = threadIdx.x;
  float p0 = pos[(size_t)i*PP], p1 = pos[(size_t)i*PP+1], p2 = pos[(size_t)i*PP+2];
  size_t idx = (size_t)i*HH + c;
  float v = (float)attn[idx] + p0*WP[c] + p1*WP[HH+c] + p2*WP[2*HH+c] + b_hp[c];
  attn[idx] = (bf16_t)tanhf(v);
}

// ---------------- fused l2norm(current_h) + time-gate h update ----------------
__global__ __launch_bounds__(256) void l2up_k(const float* __restrict__ nh2, const float* __restrict__ gate,
    float* __restrict__ h, bf16_t* __restrict__ hb){
  int i = blockIdx.x, c = threadIdx.x;
  size_t idx = (size_t)i*HH + c;
  float v = nh2[idx];
  float ss = v*v;
  #pragma unroll
  for (int o=32;o;o>>=1) ss += __shfl_down(ss, o);
  __shared__ float red[4];
  if ((threadIdx.x & 63)==0) red[threadIdx.x>>6] = ss;
  __syncthreads();
  float tot = red[0]+red[1]+red[2]+red[3];
  float curn = v / fmaxf(sqrtf(tot), 1e-12f);
  float s = sigm(gate[idx]);
  float hn = s*curn + (1.f-s)*h[idx];
  h[idx] = hn;
  hb[idx] = (bf16_t)hn;
}

// ---------------- out write: out = sig(gate)*global_h + (1-sig)*h ----------------
__global__ __launch_bounds__(256) void out_write_k(const float* __restrict__ h, const float* __restrict__ gh,
    const float* __restrict__ gate, float* __restrict__ outp){
  int i = blockIdx.x, c = threadIdx.x;
  size_t idx = (size_t)i*HH + c;
  float s = sigm(gate[idx]);
  outp[idx] = s*gh[idx] + (1.f-s)*h[idx];
}

extern "C" void kernel_launch(void* const* d_in, const int* in_sizes, int n_in,
                              void* d_out, int out_size, void* d_ws, size_t ws_size,
                              hipStream_t stream) {
  const int*   src     = (const int*)  d_in[0];
  const int*   dst     = (const int*)  d_in[1];
  const int*   etype   = (const int*)  d_in[2];
  const int*   r_to_e  = (const int*)  d_in[3];
  const int*   r_seg   = (const int*)  d_in[4];
  const float* pos_enc = (const float*)d_in[5];
  const float* dyn_emb = (const float*)d_in[6];
  const float* emb_rel = (const float*)d_in[7];
  const float* gW_ih   = (const float*)d_in[8];
  const float* gW_hh   = (const float*)d_in[9];
  const float* gb_ih   = (const float*)d_in[10];
  const float* gb_hh   = (const float*)d_in[11];
  const float* W_neigh = (const float*)d_in[12];
  const float* W_loop  = (const float*)d_in[13];
  const float* W_evolve= (const float*)d_in[14];
  const float* W_hp    = (const float*)d_in[15];
  const float* b_hp    = (const float*)d_in[16];
  const float* W_v     = (const float*)d_in[17];
  const float* b_v     = (const float*)d_in[18];
  const float* W_o     = (const float*)d_in[19];
  const float* b_o     = (const float*)d_in[20];
  const float* time_W  = (const float*)d_in[21];
  const float* time_b  = (const float*)d_in[22];
  const float* glob_W  = (const float*)d_in[23];
  const float* glob_b  = (const float*)d_in[24];
  float* out = (float*)d_out;
  (void)in_sizes; (void)n_in; (void)out_size; (void)ws_size;

  char* ws = (char*)d_ws;
  size_t off = 0;
  auto allocB = [&](size_t bytes)->char*{
    char* pp = ws + off; off += (bytes + 255) & ~(size_t)255;
    return pp;
  };
  float*  h      = (float*) allocB(NHf*4);
  float*  nh2    = (float*) allocB(NHf*4);
  float*  tmp    = (float*) allocB(NHf*4);          // aliased: le_bf [N][512] bf16, gate buffer
  float*  gh     = (float*) allocB(NHf*4);
  bf16_t* h_bf   = (bf16_t*)allocB(NHf*2);
  bf16_t* nh_bf  = (bf16_t*)allocB(NHf*2);
  bf16_t* nh2_bf = (bf16_t*)allocB(NHf*2);
  bf16_t* tmp_bf = (bf16_t*)allocB(NHf*2);          // aliased: vh_bf
  bf16_t* agg_bf = (bf16_t*)allocB(NHf*2);          // aliased: attn_bf
  bf16_t* le_bf  = (bf16_t*)tmp;
  bf16_t* vh_bf  = tmp_bf;
  bf16_t* attn_bf= agg_bf;

  float* h0    = (float*)allocB((size_t)RR*HH*4);
  float* xin   = (float*)allocB((size_t)RR*512*4);
  float* gi    = (float*)allocB((size_t)RR*768*4);
  float* ghb   = (float*)allocB((size_t)RR*768*4);
  float* W_ihT = (float*)allocB((size_t)512*768*4);
  float* W_hhT = (float*)allocB((size_t)256*768*4);
  float* WP    = (float*)allocB((size_t)PP*HH*4);
  bf16_t* neighT = (bf16_t*)allocB((size_t)2*HH*HH*2);
  bf16_t* levT   = (bf16_t*)allocB((size_t)2*512*HH*2);
  bf16_t* whpT   = (bf16_t*)allocB((size_t)HH*HH*2);
  bf16_t* wvT    = (bf16_t*)allocB((size_t)HH*HH*2);
  bf16_t* woT    = (bf16_t*)allocB((size_t)HH*HH*2);
  bf16_t* timT   = (bf16_t*)allocB((size_t)HH*HH*2);
  bf16_t* globT  = (bf16_t*)allocB((size_t)HH*HH*2);
  int* rcnt    = (int*)allocB(461*4);
  int* rstart  = (int*)allocB(461*4);
  int* rcur    = (int*)allocB(461*4);
  int* rbucket = (int*)allocB((size_t)EE*4);
  float* deg   = (float*)allocB((size_t)NN*4);

  const int MT = (NN + 127)/128;   // 391 row tiles

  // ---- setup: weight prep + initial h ----
  transpose_k<<<dim3(512/32, 768/32), 256, 0, stream>>>(gW_ih, W_ihT, 768, 512);
  transpose_k<<<dim3(256/32, 768/32), 256, 0, stream>>>(gW_hh, W_hhT, 768, 256);
  for (int l=0;l<2;l++){
    tconv_bf_k<<<dim3(8,8), 256, 0, stream>>>(W_neigh + (size_t)l*HH*HH, neighT + (size_t)l*HH*HH);
    tconv_bf_k<<<dim3(8,8), 256, 0, stream>>>(W_loop  + (size_t)l*HH*HH, levT + (size_t)l*512*HH);
    tconv_bf_k<<<dim3(8,8), 256, 0, stream>>>(W_evolve+ (size_t)l*HH*HH, levT + (size_t)l*512*HH + (size_t)HH*HH);
  }
  tconv_bf_k<<<dim3(8,8), 256, 0, stream>>>(time_W, timT);
  tconv_bf_k<<<dim3(8,8), 256, 0, stream>>>(glob_W, globT);
  copy_bf_k<<<HH, 256, 0, stream>>>(W_v, wvT, 256);
  copy_bf_k<<<HH, 256, 0, stream>>>(W_o, woT, 256);
  copy_bf_k<<<HH, 256, 0, stream>>>(W_hp, whpT, 259);
  whp_pos_k<<<1, 256, 0, stream>>>(W_hp, WP);
  l2norm_k<<<NN, 256, 0, stream>>>(dyn_emb, h, h_bf);
  hipMemcpyAsync(h0, emb_rel, (size_t)RR*HH*4, hipMemcpyDeviceToDevice, stream);

  for (int t=0; t<TT; t++){
    const int* srcT = src + (size_t)t*EE;
    const int* dstT = dst + (size_t)t*EE;
    const int* etyT = etype + (size_t)t*EE;
    const int* rteT = r_to_e + (size_t)t*EE;
    const int* rsgT = r_seg + (size_t)t*EE;
    const float* posT = pos_enc + (size_t)t*NN*PP;

    // ---- relation CSR + mean + GRU ----
    hipMemsetAsync(rcnt, 0, 461*4, stream);
    hist_r_k<<<(EE+255)/256, 256, 0, stream>>>(rsgT, rcnt);
    scan_r_k<<<1, 512, 0, stream>>>(rcnt, rstart);
    hipMemcpyAsync(rcur, rstart, 461*4, hipMemcpyDeviceToDevice, stream);
    fill_r_k<<<(EE+255)/256, 256, 0, stream>>>(rsgT, rcur, rbucket);
    rmean_k<<<RR, 256, 0, stream>>>(rstart, rbucket, rteT, h_bf, emb_rel, xin);
    sgemm_k<<<dim3(4,12), 256, 0, stream>>>(xin, W_ihT, gi, gb_ih, RR, 768, 512);
    sgemm_k<<<dim3(4,12), 256, 0, stream>>>(h0,  W_hhT, ghb, gb_hh, RR, 768, 256);
    gru_gate_k<<<RR, 256, 0, stream>>>(gi, ghb, h0);

    // ---- degrees ----
    hipMemsetAsync(deg, 0, (size_t)NN*4, stream);
    hist_deg_k<<<(EE+255)/256, 256, 0, stream>>>(dstT, deg);

    // ---- RGCN layers ----
    const bf16_t* nin_bf = h_bf;
    for (int l=0; l<2; l++){
      hipMemsetAsync(tmp, 0, NHf*4, stream);
      scatter_msg_k<<<(EE*64+255)/256, 256, 0, stream>>>(nin_bf, h0, srcT, dstT, etyT, tmp);
      f2b_k<<<((int)(NHf/8)+255)/256, 256, 0, stream>>>(tmp, tmp_bf, (int)(NHf/8));
      mgemm_k<0,1,0><<<dim3(MT,2), 256, 0, stream>>>(tmp_bf, neighT + (size_t)l*HH*HH,
                                                     nullptr, agg_bf, nullptr, NN, 256, 256);
      mgemm_k<0,1,0><<<dim3(MT,4), 256, 0, stream>>>(nin_bf, levT + (size_t)l*512*HH,
                                                     nullptr, le_bf, nullptr, NN, 512, 256);
      if (l == 0)
        combine_k<<<NN, 256, 0, stream>>>(agg_bf, le_bf, deg, nullptr, nh_bf);
      else
        combine_k<<<NN, 256, 0, stream>>>(agg_bf, le_bf, deg, nh2, nh2_bf);
      nin_bf = nh_bf;
    }

    // ---- attention chain ----
    mgemm_k<0,1,0><<<dim3(MT,2), 256, 0, stream>>>(nh2_bf, whpT, nullptr, attn_bf, nullptr, NN, 256, 256);
    attn_fix_k<<<NN, 256, 0, stream>>>(attn_bf, posT, WP, b_hp);
    mgemm_k<0,1,1><<<dim3(MT,2), 256, 0, stream>>>(attn_bf, wvT, nullptr, vh_bf, b_v, NN, 256, 256);
    mgemm_k<1,0,1><<<dim3(MT,2), 256, 0, stream>>>(vh_bf, woT, gh, nullptr, b_o, NN, 256, 256);

    // ---- time gate (pre-update h), fused norm+update, glob gate, out ----
    mgemm_k<1,0,1><<<dim3(MT,2), 256, 0, stream>>>(h_bf, timT, tmp, nullptr, time_b, NN, 256, 256);
    l2up_k<<<NN, 256, 0, stream>>>(nh2, tmp, h, h_bf);
    mgemm_k<1,0,1><<<dim3(MT,2), 256, 0, stream>>>(h_bf, globT, tmp, nullptr, glob_b, NN, 256, 256);
    out_write_k<<<NN, 256, 0, stream>>>(h, gh, tmp, out + (size_t)t*NHf);
  }
}

// Round 3
// 2573.412 us; speedup vs baseline: 2.8633x; 1.7026x over previous
//
#include <hip/hip_runtime.h>
#include <math.h>

#define NN 50000
#define HH 256
#define RR 460
#define TT 3
#define EE 100000
#define PP 3
#define SLOPE 0.22916666666666666f

typedef __bf16 bf16_t;
typedef bf16_t bf16x8 __attribute__((ext_vector_type(8)));
typedef float f32x4 __attribute__((ext_vector_type(4)));

static const size_t NHf = (size_t)NN * HH;   // 12.8M elements

__device__ __forceinline__ float sigm(float x){ return 1.0f/(1.0f+__expf(-x)); }

__device__ __forceinline__ void gload_lds16(const void* g, void* l){
  __builtin_amdgcn_global_load_lds((const __attribute__((address_space(1))) void*)g,
                                   (__attribute__((address_space(3))) void*)l, 16, 0, 0);
}

// ---------------- f32 transpose (GRU weights): out[K][M] = in[M][K]^T ----------------
__global__ __launch_bounds__(256) void transpose_k(const float* __restrict__ in,
                                                   float* __restrict__ out, int M, int K){
  __shared__ float tile[32][33];
  int k0 = blockIdx.x*32, m0 = blockIdx.y*32;
  int tx = threadIdx.x & 31, ty = threadIdx.x >> 5;
  #pragma unroll
  for (int j=0;j<4;j++){
    int m = m0 + ty + j*8, k = k0 + tx;
    tile[ty+j*8][tx] = (m<M && k<K) ? in[(size_t)m*K+k] : 0.f;
  }
  __syncthreads();
  #pragma unroll
  for (int j=0;j<4;j++){
    int k = k0 + ty + j*8, m = m0 + tx;
    if (k<K && m<M) out[(size_t)k*M+m] = tile[tx][ty+j*8];
  }
}

// ---------------- transpose+convert 256x256 f32 -> bf16: out[n*256+k] = in[k*256+n] ----------------
__global__ __launch_bounds__(256) void tconv_bf_k(const float* __restrict__ in, bf16_t* __restrict__ outp){
  __shared__ float tile[32][33];
  int n0 = blockIdx.x*32, k0 = blockIdx.y*32;
  int tx = threadIdx.x & 31, ty = threadIdx.x >> 5;
  #pragma unroll
  for (int j=0;j<4;j++)
    tile[ty+j*8][tx] = in[(size_t)(k0+ty+j*8)*256 + n0+tx];
  __syncthreads();
  #pragma unroll
  for (int j=0;j<4;j++)
    outp[(size_t)(n0+ty+j*8)*256 + k0+tx] = (bf16_t)tile[tx][ty+j*8];
}

// ---------------- row copy+convert: out[r][c] = (bf16)in[r*Cin + c], c<256 ----------------
__global__ __launch_bounds__(256) void copy_bf_k(const float* __restrict__ in, bf16_t* __restrict__ outp, int Cin){
  int r = blockIdx.x, c = threadIdx.x;
  outp[(size_t)r*HH + c] = (bf16_t)in[(size_t)r*Cin + c];
}

// WP[p][j] = W_hp[j*259 + 256 + p]
__global__ __launch_bounds__(256) void whp_pos_k(const float* __restrict__ W_hp, float* __restrict__ WP){
  int j = threadIdx.x;
  #pragma unroll
  for (int p=0;p<PP;p++) WP[p*HH + j] = W_hp[(size_t)j*259 + HH + p];
}

// ---------------- f32 SGEMM (GRU only): C[M][N] = A[M][K] @ B[K][N] + bias ----------------
__global__ __launch_bounds__(256) void sgemm_k(const float* __restrict__ A, const float* __restrict__ B,
                                               float* __restrict__ C, const float* __restrict__ bias,
                                               int M, int N, int K){
  __shared__ float As[16][128];
  __shared__ float Bs[16][64];
  int tid = threadIdx.x;
  int tx = tid & 15, ty = tid >> 4;
  int rowBase = blockIdx.x * 128;
  int colBase = blockIdx.y * 64;
  float acc[8][4];
  #pragma unroll
  for (int i=0;i<8;i++)
    #pragma unroll
    for (int j=0;j<4;j++) acc[i][j]=0.f;
  for (int k0=0;k0<K;k0+=16){
    #pragma unroll
    for (int ss=0; ss<2; ss++){
      int s = tid + ss*256;
      int r = s >> 2;
      int kk = (s & 3)*4;
      float4 v = make_float4(0.f,0.f,0.f,0.f);
      int grow = rowBase + r;
      if (grow < M) v = *(const float4*)(A + (size_t)grow*K + k0 + kk);
      As[kk+0][r]=v.x; As[kk+1][r]=v.y; As[kk+2][r]=v.z; As[kk+3][r]=v.w;
    }
    {
      int r = tid >> 4, cc = (tid & 15)*4;
      float4 v = *(const float4*)(B + (size_t)(k0+r)*N + colBase + cc);
      *(float4*)&Bs[r][cc] = v;
    }
    __syncthreads();
    #pragma unroll
    for (int kk=0;kk<16;kk++){
      float a[8], b[4];
      *(float4*)&a[0] = *(const float4*)&As[kk][ty*8];
      *(float4*)&a[4] = *(const float4*)&As[kk][ty*8+4];
      *(float4*)&b[0] = *(const float4*)&Bs[kk][tx*4];
      #pragma unroll
      for (int i=0;i<8;i++)
        #pragma unroll
        for (int j=0;j<4;j++)
          acc[i][j] = fmaf(a[i], b[j], acc[i][j]);
    }
    __syncthreads();
  }
  float4 bb = make_float4(0.f,0.f,0.f,0.f);
  if (bias) bb = *(const float4*)(bias + colBase + tx*4);
  #pragma unroll
  for (int i=0;i<8;i++){
    int gr = rowBase + ty*8 + i;
    if (gr >= M) continue;
    float4 v = make_float4(acc[i][0]+bb.x, acc[i][1]+bb.y, acc[i][2]+bb.z, acc[i][3]+bb.w);
    *(float4*)(C + (size_t)gr*N + colBase + tx*4) = v;
  }
}

// ---------------- bf16 MFMA GEMM: C[M][N] = A[M][K] @ Bt[N][K]^T ----------------
template<int WF32, int WBF, int HASB>
__global__ __launch_bounds__(256) void mgemm_k(const bf16_t* __restrict__ A, const bf16_t* __restrict__ Bt,
    float* __restrict__ C, bf16_t* __restrict__ Cb, const float* __restrict__ bias,
    int M, int N, int K){
  __shared__ bf16_t As[128*64];
  __shared__ bf16_t Bs[128*64];
  int tid = threadIdx.x;
  int lane = tid & 63, w = tid >> 6;
  int wm = w >> 1, wn = w & 1;
  int rowBase = blockIdx.x * 128;
  int colBase = blockIdx.y * 128;
  f32x4 acc[4][4] = {};

  int lrow = lane >> 3;          // 0..7 within the wave's 8-row group
  int p    = lane & 7;           // phys 16B seg
  for (int k0 = 0; k0 < K; k0 += 64){
    #pragma unroll
    for (int c = 0; c < 4; c++){
      int r = c*32 + w*8 + lrow;               // tile row 0..127
      int s = p ^ (r & 7);                     // logical seg to fetch
      int ga = min(rowBase + r, M-1);          // clamp: garbage rows feed unused acc rows only
      gload_lds16(A + (size_t)ga*K + k0 + s*8, As + (size_t)(c*32 + w*8)*64);
      int gb = colBase + r;                    // N is always a multiple of 128 here
      gload_lds16(Bt + (size_t)gb*K + k0 + s*8, Bs + (size_t)(c*32 + w*8)*64);
    }
    asm volatile("s_waitcnt vmcnt(0)" ::: "memory");
    __syncthreads();
    #pragma unroll
    for (int kk = 0; kk < 2; kk++){
      bf16x8 af[4], bfr[4];
      int sg = kk*4 + (lane >> 4);             // logical seg 0..7
      #pragma unroll
      for (int i = 0; i < 4; i++){
        int r = wm*64 + i*16 + (lane & 15);
        af[i] = *(const bf16x8*)(As + r*64 + (sg ^ (r & 7))*8);
      }
      #pragma unroll
      for (int j = 0; j < 4; j++){
        int rn = wn*64 + j*16 + (lane & 15);
        bfr[j] = *(const bf16x8*)(Bs + rn*64 + (sg ^ (rn & 7))*8);
      }
      #pragma unroll
      for (int i = 0; i < 4; i++)
        #pragma unroll
        for (int j = 0; j < 4; j++)
          acc[i][j] = __builtin_amdgcn_mfma_f32_16x16x32_bf16(af[i], bfr[j], acc[i][j], 0, 0, 0);
    }
    __syncthreads();
  }
  #pragma unroll
  for (int j = 0; j < 4; j++){
    int col = colBase + wn*64 + j*16 + (lane & 15);
    float bv = 0.f;
    if (HASB) bv = bias[col];
    #pragma unroll
    for (int i = 0; i < 4; i++){
      int row0 = rowBase + wm*64 + i*16 + ((lane >> 4) << 2);
      #pragma unroll
      for (int q = 0; q < 4; q++){
        int gr = row0 + q;
        if (gr < M){
          float v = acc[i][j][q] + bv;
          if (WF32) C[(size_t)gr*N + col] = v;
          if (WBF)  Cb[(size_t)gr*N + col] = (bf16_t)v;
        }
      }
    }
  }
}

// ---------------- row-wise L2 normalize -> f32 + bf16 (setup) ----------------
__global__ __launch_bounds__(256) void l2norm_k(const float* __restrict__ in, float* __restrict__ outf,
                                                bf16_t* __restrict__ outb){
  int i = blockIdx.x, c = threadIdx.x;
  size_t idx = (size_t)i*HH + c;
  float v = in[idx];
  float ss = v*v;
  #pragma unroll
  for (int o=32;o;o>>=1) ss += __shfl_down(ss, o);
  __shared__ float red[4];
  if ((threadIdx.x & 63)==0) red[threadIdx.x>>6] = ss;
  __syncthreads();
  float tot = red[0]+red[1]+red[2]+red[3];
  float nv = v / fmaxf(sqrtf(tot), 1e-12f);
  outf[idx] = nv;
  outb[idx] = (bf16_t)nv;
}

// ---------------- generic histogram ----------------
__global__ __launch_bounds__(256) void hist_k(const int* __restrict__ keys, int* __restrict__ cnt, int n){
  int e = blockIdx.x*256 + threadIdx.x;
  if (e < n) atomicAdd(cnt + keys[e], 1);
}

// ---------------- single-block chunked exclusive scan, start[n] = total ----------------
__global__ __launch_bounds__(1024) void scan_big_k(const int* __restrict__ cnt, int* __restrict__ start, int n){
  __shared__ int s[1024];
  __shared__ int carry;
  if (threadIdx.x == 0) carry = 0;
  __syncthreads();
  for (int base = 0; base < n; base += 1024){
    int t = base + threadIdx.x;
    int v = (t < n) ? cnt[t] : 0;
    s[threadIdx.x] = v;
    __syncthreads();
    for (int off = 1; off < 1024; off <<= 1){
      int x = (threadIdx.x >= off) ? s[threadIdx.x - off] : 0;
      __syncthreads();
      s[threadIdx.x] += x;
      __syncthreads();
    }
    if (t < n) start[t] = carry + s[threadIdx.x] - v;
    __syncthreads();
    if (threadIdx.x == 1023) carry += s[1023];
    __syncthreads();
  }
  if (threadIdx.x == 0) start[n] = carry;
}

// ---------------- relation CSR fill: store r_to_e directly ----------------
__global__ __launch_bounds__(256) void fill_r_k(const int* __restrict__ r_seg, const int* __restrict__ r_to_e,
                                                int* __restrict__ cur, int* __restrict__ rnode){
  int e = blockIdx.x*256 + threadIdx.x;
  if (e < EE){ int pp = atomicAdd(cur + r_seg[e], 1); rnode[pp] = r_to_e[e]; }
}

// ---------------- dst CSR fill: store (src, etype) pairs ----------------
__global__ __launch_bounds__(256) void fill_dst_k(const int* __restrict__ dst, const int* __restrict__ src,
    const int* __restrict__ ety, int* __restrict__ cur,
    int* __restrict__ dsrc, int* __restrict__ dety){
  int e = blockIdx.x*256 + threadIdx.x;
  if (e < EE){
    int pp = atomicAdd(cur + dst[e], 1);
    dsrc[pp] = src[e];
    dety[pp] = ety[e];
  }
}

// per-relation mean of h rows + xin build: xin[r] = [emb_rel[r] | mean]
__global__ __launch_bounds__(256) void rmean_k(const int* __restrict__ rstart, const int* __restrict__ rnode,
    const bf16_t* __restrict__ hb, const float* __restrict__ emb_rel, float* __restrict__ xin){
  int r = blockIdx.x, c = threadIdx.x;
  int s0 = rstart[r], s1 = rstart[r+1];
  float acc = 0.f;
  for (int i = s0; i < s1; i++){
    int v = rnode[i];
    acc += (float)hb[(size_t)v*HH + c];
  }
  int cnt = s1 - s0;
  xin[(size_t)r*512 + c] = emb_rel[(size_t)r*HH + c];
  xin[(size_t)r*512 + HH + c] = (cnt > 0) ? acc/(float)cnt : 0.f;
}

// ---------------- GRU gates + row l2norm, in-place h0 (f32) ----------------
__global__ __launch_bounds__(256) void gru_gate_k(const float* __restrict__ gi,
    const float* __restrict__ ghb, float* __restrict__ h0){
  int r = blockIdx.x, c = threadIdx.x;
  float ir = gi[(size_t)r*768 + c],       hr = ghb[(size_t)r*768 + c];
  float iz = gi[(size_t)r*768 + 256 + c], hz = ghb[(size_t)r*768 + 256 + c];
  float in_ = gi[(size_t)r*768 + 512 + c], hn = ghb[(size_t)r*768 + 512 + c];
  float rg = sigm(ir + hr);
  float z  = sigm(iz + hz);
  float n  = tanhf(in_ + rg*hn);
  float hp = h0[(size_t)r*HH + c];
  float v = (1.f - z)*n + z*hp;
  float ss = v*v;
  #pragma unroll
  for (int o=32;o;o>>=1) ss += __shfl_down(ss, o);
  __shared__ float red[4];
  if ((threadIdx.x & 63)==0) red[threadIdx.x>>6] = ss;
  __syncthreads();
  float tot = red[0]+red[1]+red[2]+red[3];
  h0[(size_t)r*HH + c] = v / fmaxf(sqrtf(tot), 1e-12f);
}

// ---------------- dst-gather of messages: out[d] = sum_{e in in(d)} (nh[src_e] + h0[ety_e]), bf16 ----------------
// one wave per dst node, 4 dsts per block; lane owns 4 columns.
__global__ __launch_bounds__(256) void gather_msg_k(const bf16_t* __restrict__ nhb,
    const float* __restrict__ h0, const int* __restrict__ dstart,
    const int* __restrict__ dsrc, const int* __restrict__ dety,
    bf16_t* __restrict__ outb){
  int w = threadIdx.x >> 6, ln = threadIdx.x & 63;
  int d = blockIdx.x*4 + w;
  if (d >= NN) return;
  int s0 = dstart[d], s1 = dstart[d+1];
  float a0=0.f, a1=0.f, a2=0.f, a3=0.f;
  for (int i = s0; i < s1; i++){
    int s = dsrc[i], r = dety[i];
    uint2 raw = *(const uint2*)(nhb + (size_t)s*HH + ln*4);
    float4 b = *(const float4*)(h0 + (size_t)r*HH + ln*4);
    a0 += __uint_as_float((raw.x & 0xffffu) << 16) + b.x;
    a1 += __uint_as_float(raw.x & 0xffff0000u)     + b.y;
    a2 += __uint_as_float((raw.y & 0xffffu) << 16) + b.z;
    a3 += __uint_as_float(raw.y & 0xffff0000u)     + b.w;
  }
  bf16_t o[4] = { (bf16_t)a0, (bf16_t)a1, (bf16_t)a2, (bf16_t)a3 };
  *(uint2*)(outb + (size_t)d*HH + ln*4) = *(const uint2*)o;
}

// ---------------- layer combine: out = leaky(agg/deg + (deg>0 ? loop : evolve)) ----------------
__global__ __launch_bounds__(256) void combine_k(const bf16_t* __restrict__ agg, const bf16_t* __restrict__ le,
    const int* __restrict__ dcnt, float* __restrict__ outf, bf16_t* __restrict__ outb){
  int i = blockIdx.x, c = threadIdx.x;
  int d = dcnt[i];
  size_t idx = (size_t)i*HH + c;
  float a  = (d > 0) ? (float)agg[idx] / (float)d : 0.f;
  float lp = (d > 0) ? (float)le[(size_t)i*512 + c] : (float)le[(size_t)i*512 + HH + c];
  float pre = a + lp;
  float v = (pre >= 0.f) ? pre : SLOPE*pre;
  if (outf) outf[idx] = v;
  outb[idx] = (bf16_t)v;
}

// ---------------- attention pos-fix + tanh (in-place bf16) ----------------
__global__ __launch_bounds__(256) void attn_fix_k(bf16_t* __restrict__ attn, const float* __restrict__ pos,
    const float* __restrict__ WP, const float* __restrict__ b_hp){
  int i = blockIdx.x, c = threadIdx.x;
  float p0 = pos[(size_t)i*PP], p1 = pos[(size_t)i*PP+1], p2 = pos[(size_t)i*PP+2];
  size_t idx = (size_t)i*HH + c;
  float v = (float)attn[idx] + p0*WP[c] + p1*WP[HH+c] + p2*WP[2*HH+c] + b_hp[c];
  attn[idx] = (bf16_t)tanhf(v);
}

// ---------------- fused l2norm(current_h) + time-gate h update ----------------
__global__ __launch_bounds__(256) void l2up_k(const float* __restrict__ nh2, const float* __restrict__ gate,
    float* __restrict__ h, bf16_t* __restrict__ hb){
  int i = blockIdx.x, c = threadIdx.x;
  size_t idx = (size_t)i*HH + c;
  float v = nh2[idx];
  float ss = v*v;
  #pragma unroll
  for (int o=32;o;o>>=1) ss += __shfl_down(ss, o);
  __shared__ float red[4];
  if ((threadIdx.x & 63)==0) red[threadIdx.x>>6] = ss;
  __syncthreads();
  float tot = red[0]+red[1]+red[2]+red[3];
  float curn = v / fmaxf(sqrtf(tot), 1e-12f);
  float s = sigm(gate[idx]);
  float hn = s*curn + (1.f-s)*h[idx];
  h[idx] = hn;
  hb[idx] = (bf16_t)hn;
}

// ---------------- out write: out = sig(gate)*global_h + (1-sig)*h ----------------
__global__ __launch_bounds__(256) void out_write_k(const float* __restrict__ h, const float* __restrict__ gh,
    const float* __restrict__ gate, float* __restrict__ outp){
  int i = blockIdx.x, c = threadIdx.x;
  size_t idx = (size_t)i*HH + c;
  float s = sigm(gate[idx]);
  outp[idx] = s*gh[idx] + (1.f-s)*h[idx];
}

extern "C" void kernel_launch(void* const* d_in, const int* in_sizes, int n_in,
                              void* d_out, int out_size, void* d_ws, size_t ws_size,
                              hipStream_t stream) {
  const int*   src     = (const int*)  d_in[0];
  const int*   dst     = (const int*)  d_in[1];
  const int*   etype   = (const int*)  d_in[2];
  const int*   r_to_e  = (const int*)  d_in[3];
  const int*   r_seg   = (const int*)  d_in[4];
  const float* pos_enc = (const float*)d_in[5];
  const float* dyn_emb = (const float*)d_in[6];
  const float* emb_rel = (const float*)d_in[7];
  const float* gW_ih   = (const float*)d_in[8];
  const float* gW_hh   = (const float*)d_in[9];
  const float* gb_ih   = (const float*)d_in[10];
  const float* gb_hh   = (const float*)d_in[11];
  const float* W_neigh = (const float*)d_in[12];
  const float* W_loop  = (const float*)d_in[13];
  const float* W_evolve= (const float*)d_in[14];
  const float* W_hp    = (const float*)d_in[15];
  const float* b_hp    = (const float*)d_in[16];
  const float* W_v     = (const float*)d_in[17];
  const float* b_v     = (const float*)d_in[18];
  const float* W_o     = (const float*)d_in[19];
  const float* b_o     = (const float*)d_in[20];
  const float* time_W  = (const float*)d_in[21];
  const float* time_b  = (const float*)d_in[22];
  const float* glob_W  = (const float*)d_in[23];
  const float* glob_b  = (const float*)d_in[24];
  float* out = (float*)d_out;
  (void)in_sizes; (void)n_in; (void)out_size; (void)ws_size;

  char* ws = (char*)d_ws;
  size_t off = 0;
  auto allocB = [&](size_t bytes)->char*{
    char* pp = ws + off; off += (bytes + 255) & ~(size_t)255;
    return pp;
  };
  float*  h      = (float*) allocB(NHf*4);
  float*  nh2    = (float*) allocB(NHf*4);
  float*  tmp    = (float*) allocB(NHf*4);          // aliased: le_bf [N][512] bf16, gate buffer
  float*  gh     = (float*) allocB(NHf*4);
  bf16_t* h_bf   = (bf16_t*)allocB(NHf*2);
  bf16_t* nh_bf  = (bf16_t*)allocB(NHf*2);
  bf16_t* nh2_bf = (bf16_t*)allocB(NHf*2);
  bf16_t* tmp_bf = (bf16_t*)allocB(NHf*2);          // gathered messages; aliased: vh_bf
  bf16_t* agg_bf = (bf16_t*)allocB(NHf*2);          // aliased: attn_bf
  bf16_t* le_bf  = (bf16_t*)tmp;
  bf16_t* vh_bf  = tmp_bf;
  bf16_t* attn_bf= agg_bf;

  float* h0    = (float*)allocB((size_t)RR*HH*4);
  float* xin   = (float*)allocB((size_t)RR*512*4);
  float* gi    = (float*)allocB((size_t)RR*768*4);
  float* ghb   = (float*)allocB((size_t)RR*768*4);
  float* W_ihT = (float*)allocB((size_t)512*768*4);
  float* W_hhT = (float*)allocB((size_t)256*768*4);
  float* WP    = (float*)allocB((size_t)PP*HH*4);
  bf16_t* neighT = (bf16_t*)allocB((size_t)2*HH*HH*2);
  bf16_t* levT   = (bf16_t*)allocB((size_t)2*512*HH*2);
  bf16_t* whpT   = (bf16_t*)allocB((size_t)HH*HH*2);
  bf16_t* wvT    = (bf16_t*)allocB((size_t)HH*HH*2);
  bf16_t* woT    = (bf16_t*)allocB((size_t)HH*HH*2);
  bf16_t* timT   = (bf16_t*)allocB((size_t)HH*HH*2);
  bf16_t* globT  = (bf16_t*)allocB((size_t)HH*HH*2);
  int* rcnt    = (int*)allocB(461*4);
  int* rstart  = (int*)allocB(461*4);
  int* rcur    = (int*)allocB(461*4);
  int* rnode   = (int*)allocB((size_t)EE*4);
  int* dcnt    = (int*)allocB((size_t)NN*4);
  int* dstart  = (int*)allocB((size_t)(NN+1)*4);
  int* dcur    = (int*)allocB((size_t)NN*4);
  int* dsrc    = (int*)allocB((size_t)EE*4);
  int* dety    = (int*)allocB((size_t)EE*4);

  const int MT = (NN + 127)/128;   // 391 row tiles

  // ---- setup: weight prep + initial h ----
  transpose_k<<<dim3(512/32, 768/32), 256, 0, stream>>>(gW_ih, W_ihT, 768, 512);
  transpose_k<<<dim3(256/32, 768/32), 256, 0, stream>>>(gW_hh, W_hhT, 768, 256);
  for (int l=0;l<2;l++){
    tconv_bf_k<<<dim3(8,8), 256, 0, stream>>>(W_neigh + (size_t)l*HH*HH, neighT + (size_t)l*HH*HH);
    tconv_bf_k<<<dim3(8,8), 256, 0, stream>>>(W_loop  + (size_t)l*HH*HH, levT + (size_t)l*512*HH);
    tconv_bf_k<<<dim3(8,8), 256, 0, stream>>>(W_evolve+ (size_t)l*HH*HH, levT + (size_t)l*512*HH + (size_t)HH*HH);
  }
  tconv_bf_k<<<dim3(8,8), 256, 0, stream>>>(time_W, timT);
  tconv_bf_k<<<dim3(8,8), 256, 0, stream>>>(glob_W, globT);
  copy_bf_k<<<HH, 256, 0, stream>>>(W_v, wvT, 256);
  copy_bf_k<<<HH, 256, 0, stream>>>(W_o, woT, 256);
  copy_bf_k<<<HH, 256, 0, stream>>>(W_hp, whpT, 259);
  whp_pos_k<<<1, 256, 0, stream>>>(W_hp, WP);
  l2norm_k<<<NN, 256, 0, stream>>>(dyn_emb, h, h_bf);
  hipMemcpyAsync(h0, emb_rel, (size_t)RR*HH*4, hipMemcpyDeviceToDevice, stream);

  for (int t=0; t<TT; t++){
    const int* srcT = src + (size_t)t*EE;
    const int* dstT = dst + (size_t)t*EE;
    const int* etyT = etype + (size_t)t*EE;
    const int* rteT = r_to_e + (size_t)t*EE;
    const int* rsgT = r_seg + (size_t)t*EE;
    const float* posT = pos_enc + (size_t)t*NN*PP;

    // ---- relation CSR + mean + GRU ----
    hipMemsetAsync(rcnt, 0, 461*4, stream);
    hist_k<<<(EE+255)/256, 256, 0, stream>>>(rsgT, rcnt, EE);
    scan_big_k<<<1, 1024, 0, stream>>>(rcnt, rstart, RR);
    hipMemcpyAsync(rcur, rstart, 461*4, hipMemcpyDeviceToDevice, stream);
    fill_r_k<<<(EE+255)/256, 256, 0, stream>>>(rsgT, rteT, rcur, rnode);
    rmean_k<<<RR, 256, 0, stream>>>(rstart, rnode, h_bf, emb_rel, xin);
    sgemm_k<<<dim3(4,12), 256, 0, stream>>>(xin, W_ihT, gi, gb_ih, RR, 768, 512);
    sgemm_k<<<dim3(4,12), 256, 0, stream>>>(h0,  W_hhT, ghb, gb_hh, RR, 768, 256);
    gru_gate_k<<<RR, 256, 0, stream>>>(gi, ghb, h0);

    // ---- dst CSR (shared by both layers; also provides degrees) ----
    hipMemsetAsync(dcnt, 0, (size_t)NN*4, stream);
    hist_k<<<(EE+255)/256, 256, 0, stream>>>(dstT, dcnt, EE);
    scan_big_k<<<1, 1024, 0, stream>>>(dcnt, dstart, NN);
    hipMemcpyAsync(dcur, dstart, (size_t)NN*4, hipMemcpyDeviceToDevice, stream);
    fill_dst_k<<<(EE+255)/256, 256, 0, stream>>>(dstT, srcT, etyT, dcur, dsrc, dety);

    // ---- RGCN layers ----
    const bf16_t* nin_bf = h_bf;
    for (int l=0; l<2; l++){
      gather_msg_k<<<(NN+3)/4, 256, 0, stream>>>(nin_bf, h0, dstart, dsrc, dety, tmp_bf);
      mgemm_k<0,1,0><<<dim3(MT,2), 256, 0, stream>>>(tmp_bf, neighT + (size_t)l*HH*HH,
                                                     nullptr, agg_bf, nullptr, NN, 256, 256);
      mgemm_k<0,1,0><<<dim3(MT,4), 256, 0, stream>>>(nin_bf, levT + (size_t)l*512*HH,
                                                     nullptr, le_bf, nullptr, NN, 512, 256);
      if (l == 0)
        combine_k<<<NN, 256, 0, stream>>>(agg_bf, le_bf, dcnt, nullptr, nh_bf);
      else
        combine_k<<<NN, 256, 0, stream>>>(agg_bf, le_bf, dcnt, nh2, nh2_bf);
      nin_bf = nh_bf;
    }

    // ---- attention chain ----
    mgemm_k<0,1,0><<<dim3(MT,2), 256, 0, stream>>>(nh2_bf, whpT, nullptr, attn_bf, nullptr, NN, 256, 256);
    attn_fix_k<<<NN, 256, 0, stream>>>(attn_bf, posT, WP, b_hp);
    mgemm_k<0,1,1><<<dim3(MT,2), 256, 0, stream>>>(attn_bf, wvT, nullptr, vh_bf, b_v, NN, 256, 256);
    mgemm_k<1,0,1><<<dim3(MT,2), 256, 0, stream>>>(vh_bf, woT, gh, nullptr, b_o, NN, 256, 256);

    // ---- time gate (pre-update h), fused norm+update, glob gate, out ----
    mgemm_k<1,0,1><<<dim3(MT,2), 256, 0, stream>>>(h_bf, timT, tmp, nullptr, time_b, NN, 256, 256);
    l2up_k<<<NN, 256, 0, stream>>>(nh2, tmp, h, h_bf);
    mgemm_k<1,0,1><<<dim3(MT,2), 256, 0, stream>>>(h_bf, globT, tmp, nullptr, glob_b, NN, 256, 256);
    out_write_k<<<NN, 256, 0, stream>>>(h, gh, tmp, out + (size_t)t*NHf);
  }
}

// Round 4
// 1969.467 us; speedup vs baseline: 3.7413x; 1.3067x over previous
//
#include <hip/hip_runtime.h>
#include <math.h>

#define NN 50000
#define HH 256
#define RR 460
#define TT 3
#define EE 100000
#define PP 3
#define SLOPE 0.22916666666666666f

typedef __bf16 bf16_t;
typedef bf16_t bf16x8 __attribute__((ext_vector_type(8)));
typedef float f32x4 __attribute__((ext_vector_type(4)));

static const size_t NHf = (size_t)NN * HH;   // 12.8M elements

__device__ __forceinline__ float sigm(float x){ return 1.0f/(1.0f+__expf(-x)); }

__device__ __forceinline__ void gload_lds16(const void* g, void* l){
  __builtin_amdgcn_global_load_lds((const __attribute__((address_space(1))) void*)g,
                                   (__attribute__((address_space(3))) void*)l, 16, 0, 0);
}

// ---------------- f32 transpose (GRU weights): out[K][M] = in[M][K]^T ----------------
__global__ __launch_bounds__(256) void transpose_k(const float* __restrict__ in,
                                                   float* __restrict__ out, int M, int K){
  __shared__ float tile[32][33];
  int k0 = blockIdx.x*32, m0 = blockIdx.y*32;
  int tx = threadIdx.x & 31, ty = threadIdx.x >> 5;
  #pragma unroll
  for (int j=0;j<4;j++){
    int m = m0 + ty + j*8, k = k0 + tx;
    tile[ty+j*8][tx] = (m<M && k<K) ? in[(size_t)m*K+k] : 0.f;
  }
  __syncthreads();
  #pragma unroll
  for (int j=0;j<4;j++){
    int k = k0 + ty + j*8, m = m0 + tx;
    if (k<K && m<M) out[(size_t)k*M+m] = tile[tx][ty+j*8];
  }
}

// --------- transpose+convert 256x256 f32 -> bf16 with out stride: out[n*ldout+k] = in[k*256+n] ---------
__global__ __launch_bounds__(256) void tconv_bf_k(const float* __restrict__ in, bf16_t* __restrict__ outp,
                                                  int ldout){
  __shared__ float tile[32][33];
  int n0 = blockIdx.x*32, k0 = blockIdx.y*32;
  int tx = threadIdx.x & 31, ty = threadIdx.x >> 5;
  #pragma unroll
  for (int j=0;j<4;j++)
    tile[ty+j*8][tx] = in[(size_t)(k0+ty+j*8)*256 + n0+tx];
  __syncthreads();
  #pragma unroll
  for (int j=0;j<4;j++)
    outp[(size_t)(n0+ty+j*8)*ldout + k0+tx] = (bf16_t)tile[tx][ty+j*8];
}

// ---------------- row copy+convert (for x@W^T weights): out[r][c] = (bf16)in[r*Cin + c] ----------------
__global__ __launch_bounds__(256) void copy_bf_k(const float* __restrict__ in, bf16_t* __restrict__ outp, int Cin){
  int r = blockIdx.x, c = threadIdx.x;
  outp[(size_t)r*HH + c] = (bf16_t)in[(size_t)r*Cin + c];
}

// WP[p][j] = W_hp[j*259 + 256 + p]
__global__ __launch_bounds__(256) void whp_pos_k(const float* __restrict__ W_hp, float* __restrict__ WP){
  int j = threadIdx.x;
  #pragma unroll
  for (int p=0;p<PP;p++) WP[p*HH + j] = W_hp[(size_t)j*259 + HH + p];
}

// b_ov[n] = sum_j W_o[n][j]*b_v[j] + b_o[n]
__global__ __launch_bounds__(256) void bov_k(const float* __restrict__ W_o, const float* __restrict__ b_v,
                                             const float* __restrict__ b_o, float* __restrict__ b_ov){
  int n = threadIdx.x;
  float s = b_o[n];
  for (int j=0;j<256;j++) s += W_o[(size_t)n*256+j]*b_v[j];
  b_ov[n] = s;
}

// ---------------- f32 SGEMM (GRU + setup): C[M][N] = A[M][K] @ B[K][N] + bias ----------------
__global__ __launch_bounds__(256) void sgemm_k(const float* __restrict__ A, const float* __restrict__ B,
                                               float* __restrict__ C, const float* __restrict__ bias,
                                               int M, int N, int K){
  __shared__ float As[16][128];
  __shared__ float Bs[16][64];
  int tid = threadIdx.x;
  int tx = tid & 15, ty = tid >> 4;
  int rowBase = blockIdx.x * 128;
  int colBase = blockIdx.y * 64;
  float acc[8][4];
  #pragma unroll
  for (int i=0;i<8;i++)
    #pragma unroll
    for (int j=0;j<4;j++) acc[i][j]=0.f;
  for (int k0=0;k0<K;k0+=16){
    #pragma unroll
    for (int ss=0; ss<2; ss++){
      int s = tid + ss*256;
      int r = s >> 2;
      int kk = (s & 3)*4;
      float4 v = make_float4(0.f,0.f,0.f,0.f);
      int grow = rowBase + r;
      if (grow < M) v = *(const float4*)(A + (size_t)grow*K + k0 + kk);
      As[kk+0][r]=v.x; As[kk+1][r]=v.y; As[kk+2][r]=v.z; As[kk+3][r]=v.w;
    }
    {
      int r = tid >> 4, cc = (tid & 15)*4;
      float4 v = *(const float4*)(B + (size_t)(k0+r)*N + colBase + cc);
      *(float4*)&Bs[r][cc] = v;
    }
    __syncthreads();
    #pragma unroll
    for (int kk=0;kk<16;kk++){
      float a[8], b[4];
      *(float4*)&a[0] = *(const float4*)&As[kk][ty*8];
      *(float4*)&a[4] = *(const float4*)&As[kk][ty*8+4];
      *(float4*)&b[0] = *(const float4*)&Bs[kk][tx*4];
      #pragma unroll
      for (int i=0;i<8;i++)
        #pragma unroll
        for (int j=0;j<4;j++)
          acc[i][j] = fmaf(a[i], b[j], acc[i][j]);
    }
    __syncthreads();
  }
  float4 bb = make_float4(0.f,0.f,0.f,0.f);
  if (bias) bb = *(const float4*)(bias + colBase + tx*4);
  #pragma unroll
  for (int i=0;i<8;i++){
    int gr = rowBase + ty*8 + i;
    if (gr >= M) continue;
    float4 v = make_float4(acc[i][0]+bb.x, acc[i][1]+bb.y, acc[i][2]+bb.z, acc[i][3]+bb.w);
    *(float4*)(C + (size_t)gr*N + colBase + tx*4) = v;
  }
}

// ---------------- bf16 MFMA GEMM with fused epilogues ----------------
// C[M][N] = A[M][K] @ Bt[N][K]^T, BM=BN=128, BK=64, 256 threads (4 waves 2x2).
// EPI: 0 = +bias plain; 1 = leaky-relu (no bias); 2 = tanh(v + pos-term + bias) [e1=pos, e2=WP];
//      3 = gate-blend: g=sigm(v+bias), C = g*e2 + (1-g)*e1  [e1=h, e2=gh]
template<int EPI, int WF32, int WBF, int HASB>
__global__ __launch_bounds__(256) void mgemm_k(const bf16_t* __restrict__ A, const bf16_t* __restrict__ Bt,
    float* __restrict__ C, bf16_t* __restrict__ Cb, const float* __restrict__ bias,
    int M, int N, int K, const float* __restrict__ e1, const float* __restrict__ e2){
  __shared__ bf16_t As[128*64];
  __shared__ bf16_t Bs[128*64];
  int tid = threadIdx.x;
  int lane = tid & 63, w = tid >> 6;
  int wm = w >> 1, wn = w & 1;
  int rowBase = blockIdx.x * 128;
  int colBase = blockIdx.y * 128;
  f32x4 acc[4][4] = {};

  int lrow = lane >> 3;          // 0..7 within the wave's 8-row group
  int p    = lane & 7;           // phys 16B seg
  for (int k0 = 0; k0 < K; k0 += 64){
    #pragma unroll
    for (int c = 0; c < 4; c++){
      int r = c*32 + w*8 + lrow;               // tile row 0..127
      int s = p ^ (r & 7);                     // logical seg to fetch
      int ga = min(rowBase + r, M-1);          // clamp: garbage rows feed unused acc rows only
      gload_lds16(A + (size_t)ga*K + k0 + s*8, As + (size_t)(c*32 + w*8)*64);
      int gb = colBase + r;                    // N is always a multiple of 128 here
      gload_lds16(Bt + (size_t)gb*K + k0 + s*8, Bs + (size_t)(c*32 + w*8)*64);
    }
    asm volatile("s_waitcnt vmcnt(0)" ::: "memory");
    __syncthreads();
    #pragma unroll
    for (int kk = 0; kk < 2; kk++){
      bf16x8 af[4], bfr[4];
      int sg = kk*4 + (lane >> 4);             // logical seg 0..7
      #pragma unroll
      for (int i = 0; i < 4; i++){
        int r = wm*64 + i*16 + (lane & 15);
        af[i] = *(const bf16x8*)(As + r*64 + (sg ^ (r & 7))*8);
      }
      #pragma unroll
      for (int j = 0; j < 4; j++){
        int rn = wn*64 + j*16 + (lane & 15);
        bfr[j] = *(const bf16x8*)(Bs + rn*64 + (sg ^ (rn & 7))*8);
      }
      #pragma unroll
      for (int i = 0; i < 4; i++)
        #pragma unroll
        for (int j = 0; j < 4; j++)
          acc[i][j] = __builtin_amdgcn_mfma_f32_16x16x32_bf16(af[i], bfr[j], acc[i][j], 0, 0, 0);
    }
    __syncthreads();
  }
  // ---- epilogue ----
  int colv[4]; float bb[4], wp0[4], wp1[4], wp2[4];
  #pragma unroll
  for (int j = 0; j < 4; j++){
    colv[j] = colBase + wn*64 + j*16 + (lane & 15);
    bb[j] = HASB ? bias[colv[j]] : 0.f;
    if (EPI == 2){ wp0[j] = e2[colv[j]]; wp1[j] = e2[256+colv[j]]; wp2[j] = e2[512+colv[j]]; }
  }
  #pragma unroll
  for (int i = 0; i < 4; i++){
    #pragma unroll
    for (int q = 0; q < 4; q++){
      int gr = rowBase + wm*64 + i*16 + ((lane >> 4) << 2) + q;
      if (gr >= M) continue;
      float p0=0.f, p1=0.f, p2=0.f;
      if (EPI == 2){ p0 = e1[(size_t)gr*3]; p1 = e1[(size_t)gr*3+1]; p2 = e1[(size_t)gr*3+2]; }
      #pragma unroll
      for (int j = 0; j < 4; j++){
        float v = acc[i][j][q] + bb[j];
        if (EPI == 1) v = (v >= 0.f) ? v : SLOPE*v;
        if (EPI == 2) v = tanhf(v + p0*wp0[j] + p1*wp1[j] + p2*wp2[j]);
        if (EPI == 3){
          size_t idx = (size_t)gr*N + colv[j];
          float g = sigm(v);
          v = g*e2[idx] + (1.f-g)*e1[idx];
        }
        if (WF32) C[(size_t)gr*N + colv[j]] = v;
        if (WBF)  Cb[(size_t)gr*N + colv[j]] = (bf16_t)v;
      }
    }
  }
}

// ---------------- row-wise L2 normalize -> f32 + bf16 (setup) ----------------
__global__ __launch_bounds__(256) void l2norm_k(const float* __restrict__ in, float* __restrict__ outf,
                                                bf16_t* __restrict__ outb){
  int i = blockIdx.x, c = threadIdx.x;
  size_t idx = (size_t)i*HH + c;
  float v = in[idx];
  float ss = v*v;
  #pragma unroll
  for (int o=32;o;o>>=1) ss += __shfl_down(ss, o);
  __shared__ float red[4];
  if ((threadIdx.x & 63)==0) red[threadIdx.x>>6] = ss;
  __syncthreads();
  float tot = red[0]+red[1]+red[2]+red[3];
  float nv = v / fmaxf(sqrtf(tot), 1e-12f);
  outf[idx] = nv;
  outb[idx] = (bf16_t)nv;
}

// ---------------- generic histogram ----------------
__global__ __launch_bounds__(256) void hist_k(const int* __restrict__ keys, int* __restrict__ cnt, int n){
  int e = blockIdx.x*256 + threadIdx.x;
  if (e < n) atomicAdd(cnt + keys[e], 1);
}

// ---------------- hierarchical exclusive scan (3 kernels) ----------------
__global__ __launch_bounds__(1024) void scan1_k(const int* __restrict__ cnt, int* __restrict__ start,
                                                int* __restrict__ bsum, int n){
  __shared__ int s[1024];
  int t = blockIdx.x*1024 + threadIdx.x;
  int v = (t < n) ? cnt[t] : 0;
  s[threadIdx.x] = v;
  __syncthreads();
  for (int off = 1; off < 1024; off <<= 1){
    int x = (threadIdx.x >= off) ? s[threadIdx.x - off] : 0;
    __syncthreads();
    s[threadIdx.x] += x;
    __syncthreads();
  }
  if (t < n) start[t] = s[threadIdx.x] - v;          // block-local exclusive
  if (threadIdx.x == 1023) bsum[blockIdx.x] = s[1023];
}
// 1 wave scans block sums (nb <= 64); writes start[n] = grand total
__global__ __launch_bounds__(64) void scan2_k(const int* __restrict__ bsum, int* __restrict__ boff,
                                              int* __restrict__ start, int nb, int n){
  int t = threadIdx.x;
  int v = (t < nb) ? bsum[t] : 0;
  int x = v;
  #pragma unroll
  for (int off = 1; off < 64; off <<= 1){
    int y = __shfl_up(x, off);
    if (t >= off) x += y;
  }
  if (t < nb) boff[t] = x - v;
  if (t == nb-1) start[n] = x;
}
__global__ __launch_bounds__(1024) void scan3_k(int* __restrict__ start, int* __restrict__ cur,
                                                const int* __restrict__ boff, int n){
  int t = blockIdx.x*1024 + threadIdx.x;
  if (t < n){
    int v = start[t] + boff[blockIdx.x];
    start[t] = v;
    cur[t] = v;
  }
}

// ---------------- relation CSR fill: store r_to_e directly ----------------
__global__ __launch_bounds__(256) void fill_r_k(const int* __restrict__ r_seg, const int* __restrict__ r_to_e,
                                                int* __restrict__ cur, int* __restrict__ rnode){
  int e = blockIdx.x*256 + threadIdx.x;
  if (e < EE){ int pp = atomicAdd(cur + r_seg[e], 1); rnode[pp] = r_to_e[e]; }
}

// ---------------- dst CSR fill: store (src, etype) pairs ----------------
__global__ __launch_bounds__(256) void fill_dst_k(const int* __restrict__ dst, const int* __restrict__ src,
    const int* __restrict__ ety, int* __restrict__ cur,
    int* __restrict__ dsrc, int* __restrict__ dety){
  int e = blockIdx.x*256 + threadIdx.x;
  if (e < EE){
    int pp = atomicAdd(cur + dst[e], 1);
    dsrc[pp] = src[e];
    dety[pp] = ety[e];
  }
}

// per-relation mean of h rows + xin build: xin[r] = [emb_rel[r] | mean]
__global__ __launch_bounds__(256) void rmean_k(const int* __restrict__ rstart, const int* __restrict__ rnode,
    const bf16_t* __restrict__ hb, const float* __restrict__ emb_rel, float* __restrict__ xin){
  int r = blockIdx.x, c = threadIdx.x;
  int s0 = rstart[r], s1 = rstart[r+1];
  float acc = 0.f;
  for (int i = s0; i < s1; i++){
    int v = rnode[i];
    acc += (float)hb[(size_t)v*HH + c];
  }
  int cnt = s1 - s0;
  xin[(size_t)r*512 + c] = emb_rel[(size_t)r*HH + c];
  xin[(size_t)r*512 + HH + c] = (cnt > 0) ? acc/(float)cnt : 0.f;
}

// ---------------- GRU gates + row l2norm, in-place h0 (f32) + bf16 shadow ----------------
__global__ __launch_bounds__(256) void gru_gate_k(const float* __restrict__ gi,
    const float* __restrict__ ghb, float* __restrict__ h0, bf16_t* __restrict__ h0b){
  int r = blockIdx.x, c = threadIdx.x;
  float ir = gi[(size_t)r*768 + c],       hr = ghb[(size_t)r*768 + c];
  float iz = gi[(size_t)r*768 + 256 + c], hz = ghb[(size_t)r*768 + 256 + c];
  float in_ = gi[(size_t)r*768 + 512 + c], hn = ghb[(size_t)r*768 + 512 + c];
  float rg = sigm(ir + hr);
  float z  = sigm(iz + hz);
  float n  = tanhf(in_ + rg*hn);
  float hp = h0[(size_t)r*HH + c];
  float v = (1.f - z)*n + z*hp;
  float ss = v*v;
  #pragma unroll
  for (int o=32;o;o>>=1) ss += __shfl_down(ss, o);
  __shared__ float red[4];
  if ((threadIdx.x & 63)==0) red[threadIdx.x>>6] = ss;
  __syncthreads();
  float tot = red[0]+red[1]+red[2]+red[3];
  float nv = v / fmaxf(sqrtf(tot), 1e-12f);
  h0[(size_t)r*HH + c] = nv;
  h0b[(size_t)r*HH + c] = (bf16_t)nv;
}

// ---------------- gather + build fused-RGCN A matrix [N][768] ----------------
// A[d] = [ mean_{e in in(d)}(nh[src_e]+h0[ety_e]) | deg>0?nh[d]:0 | deg>0?0:nh[d] ]
__global__ __launch_bounds__(256) void gather768_k(const bf16_t* __restrict__ nin,
    const bf16_t* __restrict__ h0b, const int* __restrict__ dstart,
    const int* __restrict__ dsrc, const int* __restrict__ dety,
    bf16_t* __restrict__ A){
  int w = threadIdx.x >> 6, ln = threadIdx.x & 63;
  int d = blockIdx.x*4 + w;
  if (d >= NN) return;
  int s0 = dstart[d], s1 = dstart[d+1];
  int deg = s1 - s0;
  float a0=0.f, a1=0.f, a2=0.f, a3=0.f;
  for (int i = s0; i < s1; i++){
    int s = dsrc[i], r = dety[i];
    uint2 ra = *(const uint2*)(nin + (size_t)s*HH + ln*4);
    uint2 rb = *(const uint2*)(h0b + (size_t)r*HH + ln*4);
    a0 += __uint_as_float((ra.x & 0xffffu) << 16) + __uint_as_float((rb.x & 0xffffu) << 16);
    a1 += __uint_as_float(ra.x & 0xffff0000u)     + __uint_as_float(rb.x & 0xffff0000u);
    a2 += __uint_as_float((ra.y & 0xffffu) << 16) + __uint_as_float((rb.y & 0xffffu) << 16);
    a3 += __uint_as_float(ra.y & 0xffff0000u)     + __uint_as_float(rb.y & 0xffff0000u);
  }
  float inv = (deg > 0) ? 1.f/(float)deg : 0.f;
  bf16_t m[4] = { (bf16_t)(a0*inv), (bf16_t)(a1*inv), (bf16_t)(a2*inv), (bf16_t)(a3*inv) };
  bf16_t* Ad = A + (size_t)d*768;
  *(uint2*)(Ad + ln*4) = *(const uint2*)m;
  uint2 self = *(const uint2*)(nin + (size_t)d*HH + ln*4);
  uint2 zero; zero.x = 0u; zero.y = 0u;
  *(uint2*)(Ad + 256 + ln*4) = (deg > 0) ? self : zero;
  *(uint2*)(Ad + 512 + ln*4) = (deg > 0) ? zero : self;
}

// ---------------- fused l2norm(current_h) + time-gate h update ----------------
__global__ __launch_bounds__(256) void l2up_k(const float* __restrict__ nh2, const float* __restrict__ gate,
    float* __restrict__ h, bf16_t* __restrict__ hb){
  int i = blockIdx.x, c = threadIdx.x;
  size_t idx = (size_t)i*HH + c;
  float v = nh2[idx];
  float ss = v*v;
  #pragma unroll
  for (int o=32;o;o>>=1) ss += __shfl_down(ss, o);
  __shared__ float red[4];
  if ((threadIdx.x & 63)==0) red[threadIdx.x>>6] = ss;
  __syncthreads();
  float tot = red[0]+red[1]+red[2]+red[3];
  float curn = v / fmaxf(sqrtf(tot), 1e-12f);
  float s = sigm(gate[idx]);
  float hn = s*curn + (1.f-s)*h[idx];
  h[idx] = hn;
  hb[idx] = (bf16_t)hn;
}

extern "C" void kernel_launch(void* const* d_in, const int* in_sizes, int n_in,
                              void* d_out, int out_size, void* d_ws, size_t ws_size,
                              hipStream_t stream) {
  const int*   src     = (const int*)  d_in[0];
  const int*   dst     = (const int*)  d_in[1];
  const int*   etype   = (const int*)  d_in[2];
  const int*   r_to_e  = (const int*)  d_in[3];
  const int*   r_seg   = (const int*)  d_in[4];
  const float* pos_enc = (const float*)d_in[5];
  const float* dyn_emb = (const float*)d_in[6];
  const float* emb_rel = (const float*)d_in[7];
  const float* gW_ih   = (const float*)d_in[8];
  const float* gW_hh   = (const float*)d_in[9];
  const float* gb_ih   = (const float*)d_in[10];
  const float* gb_hh   = (const float*)d_in[11];
  const float* W_neigh = (const float*)d_in[12];
  const float* W_loop  = (const float*)d_in[13];
  const float* W_evolve= (const float*)d_in[14];
  const float* W_hp    = (const float*)d_in[15];
  const float* b_hp    = (const float*)d_in[16];
  const float* W_v     = (const float*)d_in[17];
  const float* b_v     = (const float*)d_in[18];
  const float* W_o     = (const float*)d_in[19];
  const float* b_o     = (const float*)d_in[20];
  const float* time_W  = (const float*)d_in[21];
  const float* time_b  = (const float*)d_in[22];
  const float* glob_W  = (const float*)d_in[23];
  const float* glob_b  = (const float*)d_in[24];
  float* out = (float*)d_out;
  (void)in_sizes; (void)n_in; (void)out_size; (void)ws_size;

  char* ws = (char*)d_ws;
  size_t off = 0;
  auto allocB = [&](size_t bytes)->char*{
    char* pp = ws + off; off += (bytes + 255) & ~(size_t)255;
    return pp;
  };
  float*  h      = (float*) allocB(NHf*4);
  float*  nh2    = (float*) allocB(NHf*4);
  float*  tmp    = (float*) allocB(NHf*4);          // time-gate output; head of A768 alias
  float*  gh     = (float*) allocB(NHf*4);          // global_h; tail of A768 alias
  bf16_t* h_bf   = (bf16_t*)allocB(NHf*2);
  bf16_t* nh_bf  = (bf16_t*)allocB(NHf*2);          // layer-0 out; aliased: attn_bf
  bf16_t* nh2_bf = (bf16_t*)allocB(NHf*2);
  bf16_t* A768   = (bf16_t*)tmp;                    // 76.8MB, lives in tmp+gh (dead during RGCN)
  bf16_t* attn_bf= nh_bf;                           // nh_bf dead once layer-1 GEMM done

  float* h0    = (float*)allocB((size_t)RR*HH*4);
  bf16_t* h0b  = (bf16_t*)allocB((size_t)RR*HH*2);
  float* xin   = (float*)allocB((size_t)RR*512*4);
  float* gi    = (float*)allocB((size_t)RR*768*4);
  float* ghb   = (float*)allocB((size_t)RR*768*4);
  float* W_ihT = (float*)allocB((size_t)512*768*4);
  float* W_hhT = (float*)allocB((size_t)256*768*4);
  float* WP    = (float*)allocB((size_t)PP*HH*4);
  float* WovF  = (float*)allocB((size_t)HH*HH*4);
  float* b_ov  = (float*)allocB((size_t)HH*4);
  bf16_t* bst    = (bf16_t*)allocB((size_t)2*HH*768*2);  // per-layer stacked [W_neigh;W_loop;W_evolve]^T
  bf16_t* whpT   = (bf16_t*)allocB((size_t)HH*HH*2);
  bf16_t* wovT   = (bf16_t*)allocB((size_t)HH*HH*2);
  bf16_t* timT   = (bf16_t*)allocB((size_t)HH*HH*2);
  bf16_t* globT  = (bf16_t*)allocB((size_t)HH*HH*2);
  int* rcnt    = (int*)allocB(461*4);
  int* rstart  = (int*)allocB(461*4);
  int* rcur    = (int*)allocB(461*4);
  int* rnode   = (int*)allocB((size_t)EE*4);
  int* dcnt    = (int*)allocB((size_t)NN*4);
  int* dstart  = (int*)allocB((size_t)(NN+1)*4);
  int* dcur    = (int*)allocB((size_t)NN*4);
  int* dsrc    = (int*)allocB((size_t)EE*4);
  int* dety    = (int*)allocB((size_t)EE*4);
  int* bsum    = (int*)allocB(64*4);
  int* boff    = (int*)allocB(64*4);

  const int MT = (NN + 127)/128;          // 391 row tiles
  const int NB = (NN + 1023)/1024;        // 49 scan blocks

  // ---- setup: weight prep + initial h ----
  transpose_k<<<dim3(512/32, 768/32), 256, 0, stream>>>(gW_ih, W_ihT, 768, 512);
  transpose_k<<<dim3(256/32, 768/32), 256, 0, stream>>>(gW_hh, W_hhT, 768, 256);
  for (int l=0;l<2;l++){
    tconv_bf_k<<<dim3(8,8), 256, 0, stream>>>(W_neigh + (size_t)l*HH*HH, bst + (size_t)l*HH*768,       768);
    tconv_bf_k<<<dim3(8,8), 256, 0, stream>>>(W_loop  + (size_t)l*HH*HH, bst + (size_t)l*HH*768 + 256, 768);
    tconv_bf_k<<<dim3(8,8), 256, 0, stream>>>(W_evolve+ (size_t)l*HH*HH, bst + (size_t)l*HH*768 + 512, 768);
  }
  tconv_bf_k<<<dim3(8,8), 256, 0, stream>>>(time_W, timT, 256);
  tconv_bf_k<<<dim3(8,8), 256, 0, stream>>>(glob_W, globT, 256);
  copy_bf_k<<<HH, 256, 0, stream>>>(W_hp, whpT, 259);
  whp_pos_k<<<1, 256, 0, stream>>>(W_hp, WP);
  // W_ov = W_o @ W_v (row-major result == Bt layout), b_ov = W_o@b_v + b_o
  sgemm_k<<<dim3(2,4), 256, 0, stream>>>(W_o, W_v, WovF, nullptr, 256, 256, 256);
  bov_k<<<1, 256, 0, stream>>>(W_o, b_v, b_o, b_ov);
  copy_bf_k<<<HH, 256, 0, stream>>>(WovF, wovT, 256);
  l2norm_k<<<NN, 256, 0, stream>>>(dyn_emb, h, h_bf);
  hipMemcpyAsync(h0, emb_rel, (size_t)RR*HH*4, hipMemcpyDeviceToDevice, stream);

  for (int t=0; t<TT; t++){
    const int* srcT = src + (size_t)t*EE;
    const int* dstT = dst + (size_t)t*EE;
    const int* etyT = etype + (size_t)t*EE;
    const int* rteT = r_to_e + (size_t)t*EE;
    const int* rsgT = r_seg + (size_t)t*EE;
    const float* posT = pos_enc + (size_t)t*NN*PP;

    // ---- relation CSR + mean + GRU ----
    hipMemsetAsync(rcnt, 0, 461*4, stream);
    hist_k<<<(EE+255)/256, 256, 0, stream>>>(rsgT, rcnt, EE);
    scan1_k<<<1, 1024, 0, stream>>>(rcnt, rstart, bsum, RR);
    scan2_k<<<1, 64, 0, stream>>>(bsum, boff, rstart, 1, RR);
    scan3_k<<<1, 1024, 0, stream>>>(rstart, rcur, boff, RR);
    fill_r_k<<<(EE+255)/256, 256, 0, stream>>>(rsgT, rteT, rcur, rnode);
    rmean_k<<<RR, 256, 0, stream>>>(rstart, rnode, h_bf, emb_rel, xin);
    sgemm_k<<<dim3(4,12), 256, 0, stream>>>(xin, W_ihT, gi, gb_ih, RR, 768, 512);
    sgemm_k<<<dim3(4,12), 256, 0, stream>>>(h0,  W_hhT, ghb, gb_hh, RR, 768, 256);
    gru_gate_k<<<RR, 256, 0, stream>>>(gi, ghb, h0, h0b);

    // ---- dst CSR (shared by both layers; provides degrees implicitly) ----
    hipMemsetAsync(dcnt, 0, (size_t)NN*4, stream);
    hist_k<<<(EE+255)/256, 256, 0, stream>>>(dstT, dcnt, EE);
    scan1_k<<<NB, 1024, 0, stream>>>(dcnt, dstart, bsum, NN);
    scan2_k<<<1, 64, 0, stream>>>(bsum, boff, dstart, NB, NN);
    scan3_k<<<NB, 1024, 0, stream>>>(dstart, dcur, boff, NN);
    fill_dst_k<<<(EE+255)/256, 256, 0, stream>>>(dstT, srcT, etyT, dcur, dsrc, dety);

    // ---- RGCN layers: gather A768, one fused K=768 GEMM with leaky epilogue ----
    gather768_k<<<(NN+3)/4, 256, 0, stream>>>(h_bf, h0b, dstart, dsrc, dety, A768);
    mgemm_k<1,0,1,0><<<dim3(MT,2), 256, 0, stream>>>(A768, bst, nullptr, nh_bf, nullptr,
                                                     NN, 256, 768, nullptr, nullptr);
    gather768_k<<<(NN+3)/4, 256, 0, stream>>>(nh_bf, h0b, dstart, dsrc, dety, A768);
    mgemm_k<1,1,1,0><<<dim3(MT,2), 256, 0, stream>>>(A768, bst + (size_t)HH*768, nh2, nh2_bf, nullptr,
                                                     NN, 256, 768, nullptr, nullptr);

    // ---- attention chain: tanh(cur@W_hp^T + pos + b_hp) then @W_ov^T + b_ov ----
    mgemm_k<2,0,1,1><<<dim3(MT,2), 256, 0, stream>>>(nh2_bf, whpT, nullptr, attn_bf, b_hp,
                                                     NN, 256, 256, posT, WP);
    mgemm_k<0,1,0,1><<<dim3(MT,2), 256, 0, stream>>>(attn_bf, wovT, gh, nullptr, b_ov,
                                                     NN, 256, 256, nullptr, nullptr);

    // ---- time gate (pre-update h), fused norm+update, glob gate + out blend ----
    mgemm_k<0,1,0,1><<<dim3(MT,2), 256, 0, stream>>>(h_bf, timT, tmp, nullptr, time_b,
                                                     NN, 256, 256, nullptr, nullptr);
    l2up_k<<<NN, 256, 0, stream>>>(nh2, tmp, h, h_bf);
    mgemm_k<3,1,0,1><<<dim3(MT,2), 256, 0, stream>>>(h_bf, globT, out + (size_t)t*NHf, nullptr, glob_b,
                                                     NN, 256, 256, h, gh);
  }
}

// Round 5
// 1803.727 us; speedup vs baseline: 4.0851x; 1.0919x over previous
//
#include <hip/hip_runtime.h>
#include <math.h>

#define NN 50000
#define HH 256
#define RR 460
#define TT 3
#define EE 100000
#define PP 3
#define SLOPE 0.22916666666666666f
#define NBIN (RR + NN)          // combined histogram bins: 50460

typedef __bf16 bf16_t;
typedef bf16_t bf16x8 __attribute__((ext_vector_type(8)));
typedef float f32x4 __attribute__((ext_vector_type(4)));

static const size_t NHf = (size_t)NN * HH;   // 12.8M elements

__device__ __forceinline__ float sigm(float x){ return 1.0f/(1.0f+__expf(-x)); }
__device__ __forceinline__ float leaky(float x){ return (x >= 0.f) ? x : SLOPE*x; }

__device__ __forceinline__ void gload_lds16(const void* g, void* l){
  __builtin_amdgcn_global_load_lds((const __attribute__((address_space(1))) void*)g,
                                   (__attribute__((address_space(3))) void*)l, 16, 0, 0);
}

// --------- transpose+convert 256x256 f32 -> bf16 with out stride: out[n*ldout+k] = in[k*256+n] ---------
__global__ __launch_bounds__(256) void tconv_bf_k(const float* __restrict__ in, bf16_t* __restrict__ outp,
                                                  int ldout){
  __shared__ float tile[32][33];
  int n0 = blockIdx.x*32, k0 = blockIdx.y*32;
  int tx = threadIdx.x & 31, ty = threadIdx.x >> 5;
  #pragma unroll
  for (int j=0;j<4;j++)
    tile[ty+j*8][tx] = in[(size_t)(k0+ty+j*8)*256 + n0+tx];
  __syncthreads();
  #pragma unroll
  for (int j=0;j<4;j++)
    outp[(size_t)(n0+ty+j*8)*ldout + k0+tx] = (bf16_t)tile[tx][ty+j*8];
}

// ---------------- row copy+convert: out[r*C+c] = (bf16)in[r*Cin+c] ----------------
__global__ __launch_bounds__(256) void copy_bfw_k(const float* __restrict__ in, bf16_t* __restrict__ outp,
                                                  int C, int Cin){
  int r = blockIdx.x;
  for (int c = threadIdx.x; c < C; c += 256)
    outp[(size_t)r*C + c] = (bf16_t)in[(size_t)r*Cin + c];
}

// WP[p][j] = W_hp[j*259 + 256 + p]
__global__ __launch_bounds__(256) void whp_pos_k(const float* __restrict__ W_hp, float* __restrict__ WP){
  int j = threadIdx.x;
  #pragma unroll
  for (int p=0;p<PP;p++) WP[p*HH + j] = W_hp[(size_t)j*259 + HH + p];
}

// b_ov[n] = sum_j W_o[n][j]*b_v[j] + b_o[n]
__global__ __launch_bounds__(256) void bov_k(const float* __restrict__ W_o, const float* __restrict__ b_v,
                                             const float* __restrict__ b_o, float* __restrict__ b_ov){
  int n = threadIdx.x;
  float s = b_o[n];
  for (int j=0;j<256;j++) s += W_o[(size_t)n*256+j]*b_v[j];
  b_ov[n] = s;
}

// Wdf = We - Wl (f32 256x256)
__global__ __launch_bounds__(256) void sub_k(const float* __restrict__ We, const float* __restrict__ Wl,
                                             float* __restrict__ Wd){
  size_t i = (size_t)blockIdx.x*256 + threadIdx.x;
  Wd[i] = We[i] - Wl[i];
}

// ---------------- f32 SGEMM (setup: WovF only) ----------------
__global__ __launch_bounds__(256) void sgemm_k(const float* __restrict__ A, const float* __restrict__ B,
                                               float* __restrict__ C, const float* __restrict__ bias,
                                               int M, int N, int K){
  __shared__ float As[16][128];
  __shared__ float Bs[16][64];
  int tid = threadIdx.x;
  int tx = tid & 15, ty = tid >> 4;
  int rowBase = blockIdx.x * 128;
  int colBase = blockIdx.y * 64;
  float acc[8][4];
  #pragma unroll
  for (int i=0;i<8;i++)
    #pragma unroll
    for (int j=0;j<4;j++) acc[i][j]=0.f;
  for (int k0=0;k0<K;k0+=16){
    #pragma unroll
    for (int ss=0; ss<2; ss++){
      int s = tid + ss*256;
      int r = s >> 2;
      int kk = (s & 3)*4;
      float4 v = make_float4(0.f,0.f,0.f,0.f);
      int grow = rowBase + r;
      if (grow < M) v = *(const float4*)(A + (size_t)grow*K + k0 + kk);
      As[kk+0][r]=v.x; As[kk+1][r]=v.y; As[kk+2][r]=v.z; As[kk+3][r]=v.w;
    }
    {
      int r = tid >> 4, cc = (tid & 15)*4;
      float4 v = *(const float4*)(B + (size_t)(k0+r)*N + colBase + cc);
      *(float4*)&Bs[r][cc] = v;
    }
    __syncthreads();
    #pragma unroll
    for (int kk=0;kk<16;kk++){
      float a[8], b[4];
      *(float4*)&a[0] = *(const float4*)&As[kk][ty*8];
      *(float4*)&a[4] = *(const float4*)&As[kk][ty*8+4];
      *(float4*)&b[0] = *(const float4*)&Bs[kk][tx*4];
      #pragma unroll
      for (int i=0;i<8;i++)
        #pragma unroll
        for (int j=0;j<4;j++)
          acc[i][j] = fmaf(a[i], b[j], acc[i][j]);
    }
    __syncthreads();
  }
  #pragma unroll
  for (int i=0;i<8;i++){
    int gr = rowBase + ty*8 + i;
    if (gr >= M) continue;
    float4 v = make_float4(acc[i][0], acc[i][1], acc[i][2], acc[i][3]);
    *(float4*)(C + (size_t)gr*N + colBase + tx*4) = v;
  }
}

// ---------------- bf16 MFMA GEMM with fused epilogues ----------------
// C[M][N] = A[M][K] @ Bt[N][K]^T, BM=BN=128, BK=64, 256 threads (4 waves 2x2).
// SPLITA: K=512, k<256 from A0 (stride 256), k>=256 from A1 (stride 256).
// EPI: 0 = +bias plain; 2 = tanh(v + pos + bias) [e1=pos, e2=WP];
//      3 = gate-blend: g=sigm(v+bias), out = g*e2 + (1-g)*e1;
//      4 = deg-aware leaky (degp): deg>0 -> leaky(v), else raw;
//      5 = deg0 fix: rows indirect via z (count nzp); v = leaky(Cb[zr]+v), write back.
template<int EPI, int WF32, int WBF, int HASB, int SPLITA>
__global__ __launch_bounds__(256) void mgemm_k(
    const bf16_t* __restrict__ A0, const bf16_t* __restrict__ A1,
    const bf16_t* __restrict__ Bt,
    float* __restrict__ C, bf16_t* __restrict__ Cb, const float* __restrict__ bias,
    int M, int N, int K,
    const float* __restrict__ e1, const float* __restrict__ e2,
    const int* __restrict__ degp, const int* __restrict__ z, const int* __restrict__ nzp){
  int rowBase = blockIdx.x * 128;
  int nzv = 0;
  if (EPI == 5){
    nzv = nzp[0];
    if (rowBase >= nzv) return;
  }
  __shared__ bf16_t As[128*64];
  __shared__ bf16_t Bs[128*64];
  int tid = threadIdx.x;
  int lane = tid & 63, w = tid >> 6;
  int wm = w >> 1, wn = w & 1;
  int colBase = blockIdx.y * 128;
  f32x4 acc[4][4] = {};

  int lrow = lane >> 3;          // 0..7 within the wave's 8-row group
  int p    = lane & 7;           // phys 16B seg
  int arow[4];
  #pragma unroll
  for (int c = 0; c < 4; c++){
    int gr = rowBase + c*32 + w*8 + lrow;
    if (EPI == 5) arow[c] = z[min(gr, nzv-1)];
    else          arow[c] = min(gr, M-1);
  }
  for (int k0 = 0; k0 < K; k0 += 64){
    const bf16_t* Ap; int koff; size_t lda;
    if (SPLITA){ Ap = (k0 < 256) ? A0 : A1; koff = k0 & 255; lda = 256; }
    else       { Ap = A0; koff = k0; lda = (size_t)K; }
    #pragma unroll
    for (int c = 0; c < 4; c++){
      int r = c*32 + w*8 + lrow;               // tile row 0..127
      int s = p ^ (r & 7);                     // logical seg to fetch (both-sides swizzle)
      gload_lds16(Ap + (size_t)arow[c]*lda + koff + s*8, As + (size_t)(c*32 + w*8)*64);
      int gb = colBase + r;                    // N multiple of 128 always
      gload_lds16(Bt + (size_t)gb*K + k0 + s*8, Bs + (size_t)(c*32 + w*8)*64);
    }
    asm volatile("s_waitcnt vmcnt(0)" ::: "memory");
    __syncthreads();
    #pragma unroll
    for (int kk = 0; kk < 2; kk++){
      bf16x8 af[4], bfr[4];
      int sg = kk*4 + (lane >> 4);             // logical seg 0..7
      #pragma unroll
      for (int i = 0; i < 4; i++){
        int r = wm*64 + i*16 + (lane & 15);
        af[i] = *(const bf16x8*)(As + r*64 + (sg ^ (r & 7))*8);
      }
      #pragma unroll
      for (int j = 0; j < 4; j++){
        int rn = wn*64 + j*16 + (lane & 15);
        bfr[j] = *(const bf16x8*)(Bs + rn*64 + (sg ^ (rn & 7))*8);
      }
      #pragma unroll
      for (int i = 0; i < 4; i++)
        #pragma unroll
        for (int j = 0; j < 4; j++)
          acc[i][j] = __builtin_amdgcn_mfma_f32_16x16x32_bf16(af[i], bfr[j], acc[i][j], 0, 0, 0);
    }
    __syncthreads();
  }
  // ---- epilogue ----
  int colv[4]; float bb[4], wp0[4], wp1[4], wp2[4];
  #pragma unroll
  for (int j = 0; j < 4; j++){
    colv[j] = colBase + wn*64 + j*16 + (lane & 15);
    bb[j] = HASB ? bias[colv[j]] : 0.f;
    if (EPI == 2){ wp0[j] = e2[colv[j]]; wp1[j] = e2[256+colv[j]]; wp2[j] = e2[512+colv[j]]; }
  }
  #pragma unroll
  for (int i = 0; i < 4; i++){
    #pragma unroll
    for (int q = 0; q < 4; q++){
      int grt = rowBase + wm*64 + i*16 + ((lane >> 4) << 2) + q;
      if (EPI == 5){ if (grt >= nzv) continue; }
      else         { if (grt >= M) continue; }
      int orow = (EPI == 5) ? z[grt] : grt;
      int dflag = 0;
      if (EPI == 4) dflag = degp[orow];
      float p0=0.f, p1=0.f, p2=0.f;
      if (EPI == 2){ p0 = e1[(size_t)grt*3]; p1 = e1[(size_t)grt*3+1]; p2 = e1[(size_t)grt*3+2]; }
      #pragma unroll
      for (int j = 0; j < 4; j++){
        float v = acc[i][j][q] + bb[j];
        if (EPI == 2) v = tanhf(v + p0*wp0[j] + p1*wp1[j] + p2*wp2[j]);
        if (EPI == 3){
          size_t idx = (size_t)orow*N + colv[j];
          float g = sigm(v);
          v = g*e2[idx] + (1.f-g)*e1[idx];
        }
        if (EPI == 4) v = (dflag > 0) ? leaky(v) : v;
        if (EPI == 5){
          float praw = (float)Cb[(size_t)orow*N + colv[j]];
          v = leaky(praw + v);
        }
        if (WF32) C[(size_t)orow*N + colv[j]] = v;
        if (WBF)  Cb[(size_t)orow*N + colv[j]] = (bf16_t)v;
      }
    }
  }
}

// ---------------- row-wise L2 normalize -> f32 + bf16 (setup) ----------------
__global__ __launch_bounds__(256) void l2norm_k(const float* __restrict__ in, float* __restrict__ outf,
                                                bf16_t* __restrict__ outb){
  int i = blockIdx.x, c = threadIdx.x;
  size_t idx = (size_t)i*HH + c;
  float v = in[idx];
  float ss = v*v;
  #pragma unroll
  for (int o=32;o;o>>=1) ss += __shfl_down(ss, o);
  __shared__ float red[4];
  if ((threadIdx.x & 63)==0) red[threadIdx.x>>6] = ss;
  __syncthreads();
  float tot = red[0]+red[1]+red[2]+red[3];
  float nv = v / fmaxf(sqrtf(tot), 1e-12f);
  outf[idx] = nv;
  outb[idx] = (bf16_t)nv;
}

// ---------------- combined histogram: bins [0,460) = r_seg, [460, 460+NN) = dst ----------------
__global__ __launch_bounds__(256) void hist2_k(const int* __restrict__ r_seg, const int* __restrict__ dst,
                                               int* __restrict__ cnt){
  int e = blockIdx.x*256 + threadIdx.x;
  if (e < EE) atomicAdd(cnt + r_seg[e], 1);
  else if (e < 2*EE) atomicAdd(cnt + RR + dst[e-EE], 1);
}

// ---------------- hierarchical exclusive scan (3 kernels) ----------------
__global__ __launch_bounds__(1024) void scan1_k(const int* __restrict__ cnt, int* __restrict__ start,
                                                int* __restrict__ bsum, int n){
  __shared__ int s[1024];
  int t = blockIdx.x*1024 + threadIdx.x;
  int v = (t < n) ? cnt[t] : 0;
  s[threadIdx.x] = v;
  __syncthreads();
  for (int off = 1; off < 1024; off <<= 1){
    int x = (threadIdx.x >= off) ? s[threadIdx.x - off] : 0;
    __syncthreads();
    s[threadIdx.x] += x;
    __syncthreads();
  }
  if (t < n) start[t] = s[threadIdx.x] - v;          // block-local exclusive
  if (threadIdx.x == 1023) bsum[blockIdx.x] = s[1023];
}
__global__ __launch_bounds__(64) void scan2_k(const int* __restrict__ bsum, int* __restrict__ boff,
                                              int* __restrict__ start, int nb, int n){
  int t = threadIdx.x;
  int v = (t < nb) ? bsum[t] : 0;
  int x = v;
  #pragma unroll
  for (int off = 1; off < 64; off <<= 1){
    int y = __shfl_up(x, off);
    if (t >= off) x += y;
  }
  if (t < nb) boff[t] = x - v;
  if (t == nb-1) start[n] = x;
}
__global__ __launch_bounds__(1024) void scan3_k(int* __restrict__ start, int* __restrict__ cur,
                                                const int* __restrict__ boff, int n){
  int t = blockIdx.x*1024 + threadIdx.x;
  if (t < n){
    int v = start[t] + boff[blockIdx.x];
    start[t] = v;
    cur[t] = v;
  }
}

// ---------------- combined CSR fill ----------------
__global__ __launch_bounds__(256) void fill2_k(const int* __restrict__ r_seg, const int* __restrict__ r_to_e,
    const int* __restrict__ dst, const int* __restrict__ src, const int* __restrict__ ety,
    int* __restrict__ cur, int* __restrict__ rnode, int* __restrict__ dsrc, int* __restrict__ dety){
  int e = blockIdx.x*256 + threadIdx.x;
  if (e < EE){
    int pp = atomicAdd(cur + r_seg[e], 1);
    rnode[pp] = r_to_e[e];
  } else if (e < 2*EE){
    int ee = e - EE;
    int pp = atomicAdd(cur + RR + dst[ee], 1) - EE;
    dsrc[pp] = src[ee];
    dety[pp] = ety[ee];
  }
}

// ---------------- compact deg-0 node list ----------------
__global__ __launch_bounds__(256) void compact_k(const int* __restrict__ cnt, int* __restrict__ z,
                                                 int* __restrict__ nz){
  int d = blockIdx.x*256 + threadIdx.x;
  if (d < NN && cnt[RR + d] == 0){
    int pp = atomicAdd(nz, 1);
    z[pp] = d;
  }
}

// per-relation mean of h rows + xin build (bf16): xin[r] = [emb_rel[r] | mean]
__global__ __launch_bounds__(256) void rmean_k(const int* __restrict__ rstart, const int* __restrict__ rnode,
    const bf16_t* __restrict__ hb, const float* __restrict__ emb_rel, bf16_t* __restrict__ xinb){
  int r = blockIdx.x, c = threadIdx.x;
  int s0 = rstart[r], s1 = rstart[r+1];
  float acc = 0.f, acc2 = 0.f;
  int i = s0;
  for (; i + 1 < s1; i += 2){
    acc  += (float)hb[(size_t)rnode[i]*HH + c];
    acc2 += (float)hb[(size_t)rnode[i+1]*HH + c];
  }
  if (i < s1) acc += (float)hb[(size_t)rnode[i]*HH + c];
  acc += acc2;
  int cnt = s1 - s0;
  xinb[(size_t)r*512 + c] = (bf16_t)emb_rel[(size_t)r*HH + c];
  xinb[(size_t)r*512 + HH + c] = (bf16_t)((cnt > 0) ? acc/(float)cnt : 0.f);
}

// ---------------- GRU gates + row l2norm, in-place h0 (f32) + bf16 shadow ----------------
__global__ __launch_bounds__(256) void gru_gate_k(const float* __restrict__ gi,
    const float* __restrict__ ghb, float* __restrict__ h0, bf16_t* __restrict__ h0b){
  int r = blockIdx.x, c = threadIdx.x;
  float ir = gi[(size_t)r*768 + c],       hr = ghb[(size_t)r*768 + c];
  float iz = gi[(size_t)r*768 + 256 + c], hz = ghb[(size_t)r*768 + 256 + c];
  float in_ = gi[(size_t)r*768 + 512 + c], hn = ghb[(size_t)r*768 + 512 + c];
  float rg = sigm(ir + hr);
  float z  = sigm(iz + hz);
  float n  = tanhf(in_ + rg*hn);
  float hp = h0[(size_t)r*HH + c];
  float v = (1.f - z)*n + z*hp;
  float ss = v*v;
  #pragma unroll
  for (int o=32;o;o>>=1) ss += __shfl_down(ss, o);
  __shared__ float red[4];
  if ((threadIdx.x & 63)==0) red[threadIdx.x>>6] = ss;
  __syncthreads();
  float tot = red[0]+red[1]+red[2]+red[3];
  float nv = v / fmaxf(sqrtf(tot), 1e-12f);
  h0[(size_t)r*HH + c] = nv;
  h0b[(size_t)r*HH + c] = (bf16_t)nv;
}

// ---------------- gather mean messages: Amean[d] = mean_{e in in(d)}(nh[src_e]+h0[ety_e]) ----------------
__global__ __launch_bounds__(256) void gatherM_k(const bf16_t* __restrict__ nin,
    const bf16_t* __restrict__ h0b, const int* __restrict__ start,
    const int* __restrict__ dsrc, const int* __restrict__ dety,
    bf16_t* __restrict__ Amean){
  int w = threadIdx.x >> 6, ln = threadIdx.x & 63;
  int d = blockIdx.x*4 + w;
  if (d >= NN) return;
  int s0 = start[RR + d] - EE, s1 = start[RR + d + 1] - EE;
  int deg = s1 - s0;
  float a0=0.f, a1=0.f, a2=0.f, a3=0.f;
  for (int i = s0; i < s1; i++){
    int s = dsrc[i], r = dety[i];
    uint2 ra = *(const uint2*)(nin + (size_t)s*HH + ln*4);
    uint2 rb = *(const uint2*)(h0b + (size_t)r*HH + ln*4);
    a0 += __uint_as_float((ra.x & 0xffffu) << 16) + __uint_as_float((rb.x & 0xffffu) << 16);
    a1 += __uint_as_float(ra.x & 0xffff0000u)     + __uint_as_float(rb.x & 0xffff0000u);
    a2 += __uint_as_float((ra.y & 0xffffu) << 16) + __uint_as_float((rb.y & 0xffffu) << 16);
    a3 += __uint_as_float(ra.y & 0xffff0000u)     + __uint_as_float(rb.y & 0xffff0000u);
  }
  float inv = (deg > 0) ? 1.f/(float)deg : 0.f;
  bf16_t m[4] = { (bf16_t)(a0*inv), (bf16_t)(a1*inv), (bf16_t)(a2*inv), (bf16_t)(a3*inv) };
  *(uint2*)(Amean + (size_t)d*HH + ln*4) = *(const uint2*)m;
}

// ---------------- fused l2norm(current_h) + time-gate h update ----------------
__global__ __launch_bounds__(256) void l2up_k(const float* __restrict__ nh2, const float* __restrict__ gate,
    float* __restrict__ h, bf16_t* __restrict__ hb){
  int i = blockIdx.x, c = threadIdx.x;
  size_t idx = (size_t)i*HH + c;
  float v = nh2[idx];
  float ss = v*v;
  #pragma unroll
  for (int o=32;o;o>>=1) ss += __shfl_down(ss, o);
  __shared__ float red[4];
  if ((threadIdx.x & 63)==0) red[threadIdx.x>>6] = ss;
  __syncthreads();
  float tot = red[0]+red[1]+red[2]+red[3];
  float curn = v / fmaxf(sqrtf(tot), 1e-12f);
  float s = sigm(gate[idx]);
  float hn = s*curn + (1.f-s)*h[idx];
  h[idx] = hn;
  hb[idx] = (bf16_t)hn;
}

extern "C" void kernel_launch(void* const* d_in, const int* in_sizes, int n_in,
                              void* d_out, int out_size, void* d_ws, size_t ws_size,
                              hipStream_t stream) {
  const int*   src     = (const int*)  d_in[0];
  const int*   dst     = (const int*)  d_in[1];
  const int*   etype   = (const int*)  d_in[2];
  const int*   r_to_e  = (const int*)  d_in[3];
  const int*   r_seg   = (const int*)  d_in[4];
  const float* pos_enc = (const float*)d_in[5];
  const float* dyn_emb = (const float*)d_in[6];
  const float* emb_rel = (const float*)d_in[7];
  const float* gW_ih   = (const float*)d_in[8];
  const float* gW_hh   = (const float*)d_in[9];
  const float* gb_ih   = (const float*)d_in[10];
  const float* gb_hh   = (const float*)d_in[11];
  const float* W_neigh = (const float*)d_in[12];
  const float* W_loop  = (const float*)d_in[13];
  const float* W_evolve= (const float*)d_in[14];
  const float* W_hp    = (const float*)d_in[15];
  const float* b_hp    = (const float*)d_in[16];
  const float* W_v     = (const float*)d_in[17];
  const float* b_v     = (const float*)d_in[18];
  const float* W_o     = (const float*)d_in[19];
  const float* b_o     = (const float*)d_in[20];
  const float* time_W  = (const float*)d_in[21];
  const float* time_b  = (const float*)d_in[22];
  const float* glob_W  = (const float*)d_in[23];
  const float* glob_b  = (const float*)d_in[24];
  float* out = (float*)d_out;
  (void)in_sizes; (void)n_in; (void)out_size; (void)ws_size;

  char* ws = (char*)d_ws;
  size_t off = 0;
  auto allocB = [&](size_t bytes)->char*{
    char* pp = ws + off; off += (bytes + 255) & ~(size_t)255;
    return pp;
  };
  float*  h      = (float*) allocB(NHf*4);
  float*  nh2    = (float*) allocB(NHf*4);
  float*  tmp    = (float*) allocB(NHf*4);          // Amean (bf16) aliases head; later time-gate output
  float*  gh     = (float*) allocB(NHf*4);          // global_h
  bf16_t* h_bf   = (bf16_t*)allocB(NHf*2);
  bf16_t* nh_bf  = (bf16_t*)allocB(NHf*2);          // layer-0 out; aliased: attn_bf
  bf16_t* nh2_bf = (bf16_t*)allocB(NHf*2);
  bf16_t* Amean  = (bf16_t*)tmp;
  bf16_t* attn_bf= nh_bf;

  float*  h0    = (float*) allocB((size_t)RR*HH*4);
  bf16_t* h0b   = (bf16_t*)allocB((size_t)RR*HH*2);
  bf16_t* xinb  = (bf16_t*)allocB((size_t)RR*512*2);
  float*  gi    = (float*) allocB((size_t)RR*768*4);
  float*  ghb   = (float*) allocB((size_t)RR*768*4);
  bf16_t* wihT  = (bf16_t*)allocB((size_t)768*512*2);
  bf16_t* whhT  = (bf16_t*)allocB((size_t)768*256*2);
  float*  WP    = (float*) allocB((size_t)PP*HH*4);
  float*  WovF  = (float*) allocB((size_t)HH*HH*4);
  float*  b_ov  = (float*) allocB((size_t)HH*4);
  float*  Wdf   = (float*) allocB((size_t)HH*HH*4);
  bf16_t* bst2  = (bf16_t*)allocB((size_t)2*HH*512*2);   // per-layer [Wn|Wl] transposed, ld 512
  bf16_t* wdT   = (bf16_t*)allocB((size_t)2*HH*HH*2);    // per-layer (We-Wl)^T
  bf16_t* whpT  = (bf16_t*)allocB((size_t)HH*HH*2);
  bf16_t* wovT  = (bf16_t*)allocB((size_t)HH*HH*2);
  bf16_t* timT  = (bf16_t*)allocB((size_t)HH*HH*2);
  bf16_t* globT = (bf16_t*)allocB((size_t)HH*HH*2);
  int* cnt    = (int*)allocB((size_t)(NBIN+1)*4);        // [0,460)=rel, [460,50460)=dst, [50460]=nz
  int* start  = (int*)allocB((size_t)(NBIN+1)*4);
  int* cur    = (int*)allocB((size_t)NBIN*4);
  int* rnode  = (int*)allocB((size_t)EE*4);
  int* dsrc   = (int*)allocB((size_t)EE*4);
  int* dety   = (int*)allocB((size_t)EE*4);
  int* zlist  = (int*)allocB((size_t)NN*4);
  int* bsum   = (int*)allocB(64*4);
  int* boff   = (int*)allocB(64*4);
  int* nz     = cnt + NBIN;

  const int MT  = (NN + 127)/128;          // 391 row tiles
  const int NB2 = (NBIN + 1023)/1024;      // 50 scan blocks

  // ---- setup: weight prep + initial h/h0 ----
  copy_bfw_k<<<768, 256, 0, stream>>>(gW_ih, wihT, 512, 512);
  copy_bfw_k<<<768, 256, 0, stream>>>(gW_hh, whhT, 256, 256);
  for (int l=0;l<2;l++){
    tconv_bf_k<<<dim3(8,8), 256, 0, stream>>>(W_neigh + (size_t)l*HH*HH, bst2 + (size_t)l*HH*512,       512);
    tconv_bf_k<<<dim3(8,8), 256, 0, stream>>>(W_loop  + (size_t)l*HH*HH, bst2 + (size_t)l*HH*512 + 256, 512);
    sub_k<<<256, 256, 0, stream>>>(W_evolve + (size_t)l*HH*HH, W_loop + (size_t)l*HH*HH, Wdf);
    tconv_bf_k<<<dim3(8,8), 256, 0, stream>>>(Wdf, wdT + (size_t)l*HH*HH, 256);
  }
  tconv_bf_k<<<dim3(8,8), 256, 0, stream>>>(time_W, timT, 256);
  tconv_bf_k<<<dim3(8,8), 256, 0, stream>>>(glob_W, globT, 256);
  copy_bfw_k<<<HH, 256, 0, stream>>>(W_hp, whpT, 256, 259);
  whp_pos_k<<<1, 256, 0, stream>>>(W_hp, WP);
  sgemm_k<<<dim3(2,4), 256, 0, stream>>>(W_o, W_v, WovF, nullptr, 256, 256, 256);
  bov_k<<<1, 256, 0, stream>>>(W_o, b_v, b_o, b_ov);
  copy_bfw_k<<<HH, 256, 0, stream>>>(WovF, wovT, 256, 256);
  l2norm_k<<<NN, 256, 0, stream>>>(dyn_emb, h, h_bf);
  hipMemcpyAsync(h0, emb_rel, (size_t)RR*HH*4, hipMemcpyDeviceToDevice, stream);
  copy_bfw_k<<<RR, 256, 0, stream>>>(emb_rel, h0b, 256, 256);

  for (int t=0; t<TT; t++){
    const int* srcT = src + (size_t)t*EE;
    const int* dstT = dst + (size_t)t*EE;
    const int* etyT = etype + (size_t)t*EE;
    const int* rteT = r_to_e + (size_t)t*EE;
    const int* rsgT = r_seg + (size_t)t*EE;
    const float* posT = pos_enc + (size_t)t*NN*PP;

    // ---- combined CSR build (relation bins + dst bins + nz) ----
    hipMemsetAsync(cnt, 0, (size_t)(NBIN+1)*4, stream);
    hist2_k<<<(2*EE+255)/256, 256, 0, stream>>>(rsgT, dstT, cnt);
    scan1_k<<<NB2, 1024, 0, stream>>>(cnt, start, bsum, NBIN);
    scan2_k<<<1, 64, 0, stream>>>(bsum, boff, start, NB2, NBIN);
    scan3_k<<<NB2, 1024, 0, stream>>>(start, cur, boff, NBIN);
    fill2_k<<<(2*EE+255)/256, 256, 0, stream>>>(rsgT, rteT, dstT, srcT, etyT, cur, rnode, dsrc, dety);
    compact_k<<<(NN+255)/256, 256, 0, stream>>>(cnt, zlist, nz);

    // ---- relation mean + GRU (bf16 MFMA) ----
    rmean_k<<<RR, 256, 0, stream>>>(start, rnode, h_bf, emb_rel, xinb);
    mgemm_k<0,1,0,1,0><<<dim3(4,6), 256, 0, stream>>>(xinb, nullptr, wihT, gi, nullptr, gb_ih,
        RR, 768, 512, nullptr, nullptr, nullptr, nullptr, nullptr);
    mgemm_k<0,1,0,1,0><<<dim3(4,6), 256, 0, stream>>>(h0b, nullptr, whhT, ghb, nullptr, gb_hh,
        RR, 768, 256, nullptr, nullptr, nullptr, nullptr, nullptr);
    gru_gate_k<<<RR, 256, 0, stream>>>(gi, ghb, h0, h0b);

    // ---- RGCN layer 0: mean-gather, split-A K=512 GEMM, deg0 fix ----
    gatherM_k<<<(NN+3)/4, 256, 0, stream>>>(h_bf, h0b, start, dsrc, dety, Amean);
    mgemm_k<4,0,1,0,1><<<dim3(MT,2), 256, 0, stream>>>(Amean, h_bf, bst2, nullptr, nh_bf, nullptr,
        NN, 256, 512, nullptr, nullptr, cnt + RR, nullptr, nullptr);
    mgemm_k<5,0,1,0,0><<<dim3(MT,2), 256, 0, stream>>>(h_bf, nullptr, wdT, nullptr, nh_bf, nullptr,
        NN, 256, 256, nullptr, nullptr, nullptr, zlist, nz);

    // ---- RGCN layer 1 ----
    gatherM_k<<<(NN+3)/4, 256, 0, stream>>>(nh_bf, h0b, start, dsrc, dety, Amean);
    mgemm_k<4,1,1,0,1><<<dim3(MT,2), 256, 0, stream>>>(Amean, nh_bf, bst2 + (size_t)HH*512, nh2, nh2_bf, nullptr,
        NN, 256, 512, nullptr, nullptr, cnt + RR, nullptr, nullptr);
    mgemm_k<5,1,1,0,0><<<dim3(MT,2), 256, 0, stream>>>(nh_bf, nullptr, wdT + (size_t)HH*HH, nh2, nh2_bf, nullptr,
        NN, 256, 256, nullptr, nullptr, nullptr, zlist, nz);

    // ---- attention chain ----
    mgemm_k<2,0,1,1,0><<<dim3(MT,2), 256, 0, stream>>>(nh2_bf, nullptr, whpT, nullptr, attn_bf, b_hp,
        NN, 256, 256, posT, WP, nullptr, nullptr, nullptr);
    mgemm_k<0,1,0,1,0><<<dim3(MT,2), 256, 0, stream>>>(attn_bf, nullptr, wovT, gh, nullptr, b_ov,
        NN, 256, 256, nullptr, nullptr, nullptr, nullptr, nullptr);

    // ---- time gate, fused norm+update, glob gate + out blend ----
    mgemm_k<0,1,0,1,0><<<dim3(MT,2), 256, 0, stream>>>(h_bf, nullptr, timT, tmp, nullptr, time_b,
        NN, 256, 256, nullptr, nullptr, nullptr, nullptr, nullptr);
    l2up_k<<<NN, 256, 0, stream>>>(nh2, tmp, h, h_bf);
    mgemm_k<3,1,0,1,0><<<dim3(MT,2), 256, 0, stream>>>(h_bf, nullptr, globT, out + (size_t)t*NHf, nullptr, glob_b,
        NN, 256, 256, h, gh, nullptr, nullptr, nullptr);
  }
}